// Round 8
// baseline (1060.906 us; speedup 1.0000x reference)
//
#include <hip/hip_runtime.h>
#include <hip/hip_bf16.h>
#include <math.h>

#define N_NODES 10000
#define N_EDGES 160000
#define CS 384
#define CZ 128
#define CH 192
#define NH 12
#define PQ 4
#define PV 8

typedef __hip_bfloat16 bf16;
typedef unsigned short ushort;
typedef __attribute__((ext_vector_type(8))) short short8;
typedef __attribute__((ext_vector_type(4))) short s16x4;
typedef __attribute__((ext_vector_type(4))) float f32x4;

__device__ __forceinline__ ushort cvt1(float f) {
  bf16 h = __float2bfloat16(f);
  return __builtin_bit_cast(unsigned short, h);
}
// fp32 -> bf16x8 fragment with guaranteed dwordx4 loads (idx 8-aligned)
__device__ __forceinline__ short8 lda8f(const float* p, int idx) {
  const f32x4* q = (const f32x4*)(p + idx);
  f32x4 a = q[0], b = q[1];
  short8 r;
  r[0] = (short)cvt1(a[0]); r[1] = (short)cvt1(a[1]);
  r[2] = (short)cvt1(a[2]); r[3] = (short)cvt1(a[3]);
  r[4] = (short)cvt1(b[0]); r[5] = (short)cvt1(b[1]);
  r[6] = (short)cvt1(b[2]); r[7] = (short)cvt1(b[3]);
  return r;
}
__device__ __forceinline__ float bf(ushort u) {
  return __bfloat162float(__builtin_bit_cast(bf16, u));
}

// ---- workspace layout (float offsets) ----
#define OFF_QPTS   0                              // N*144 bf16 (N*72 slots)
#define OFF_KPTS   (OFF_QPTS + N_NODES*72)        // N*144 bf16
#define OFF_VPTSH  (OFF_KPTS + N_NODES*72)        // N*288 bf16
#define OFF_SB     (OFF_VPTSH + N_NODES*144)      // N*384 bf16 (s pre-cast)
#define OFF_LOGIT  (OFF_SB + N_NODES*192)         // E*12 fp32 SORTED (becomes a after k_softmax)
#define OFF_AMAX   (OFF_LOGIT + N_EDGES*12)       // unused (kept for layout stability)
#define OFF_DENOM  (OFF_AMAX + N_NODES*12)        // unused
#define OFF_ACCO   (OFF_DENOM + N_NODES*12)       // N*192
#define OFF_ACCP   (OFF_ACCO + N_NODES*192)       // N*288
#define OFF_ACCZ   (OFF_ACCP + N_NODES*288)       // N*384
#define FP32_TOTAL (OFF_ACCZ + N_NODES*384)

// ---- swizzled weights (ushort offsets after FP32 region) ----
#define WW1S 0
#define WW2S 172032
#define WW3S 208896
#define WBS  211968
#define WV1S 214016
#define WV2S 312320
#define WV3S 349184
#define WDZS 386048
#define WQS  390144
#define WKVS 445440
#define WOS  611328
#define SWZ_TOTAL 979968

// ---- int region ----
#define IHIST   0
#define ICUR    10000
#define IROWPTR 20000
#define IPERM   30016

__global__ void k_init(float* __restrict__ ws, int* __restrict__ ib) {
  int idx = blockIdx.x * blockDim.x + threadIdx.x;
  const int ntot = N_NODES * (192 + 288 + 384);
  if (idx < ntot) ws[OFF_ACCO + idx] = 0.0f;
  if (idx < N_NODES) ib[IHIST + idx] = 0;
}

__global__ void k_cast_s(const float* __restrict__ s, ushort* __restrict__ sb) {
  int i = (blockIdx.x * 256 + threadIdx.x) * 4;
  if (i + 3 < N_NODES*CS) {
    f32x4 v = *(const f32x4*)(s + i);
    sb[i]   = cvt1(v[0]); sb[i+1] = cvt1(v[1]);
    sb[i+2] = cvt1(v[2]); sb[i+3] = cvt1(v[3]);
  }
}

// -------- merged weight swizzle (fp32 src -> bf16 B-fragment order), 11 matrices --------
struct SwzArgs {
  const float* src[11];
  int off[11], start[11], Nreal[11], NT[11];
};
__global__ void k_swz_all(SwzArgs A, ushort* __restrict__ dst, int grand) {
  int tid = blockIdx.x * blockDim.x + threadIdx.x;
  if (tid >= grand) return;
  int m = 0;
  while (m < 10 && tid >= A.start[m+1]) ++m;
  int t = tid - A.start[m];
  int j = t & 7, lane = (t >> 3) & 63, t2 = t >> 9;
  int nt = t2 % A.NT[m], kt = t2 / A.NT[m];
  int k = kt*32 + (lane >> 4)*8 + j;
  int n = nt*16 + (lane & 15);
  dst[A.off[m] + t] = (n < A.Nreal[m]) ? cvt1(A.src[m][k*A.Nreal[m] + n]) : (ushort)0;
}

// -------- counting sort by src --------
__global__ void k_hist(const int* __restrict__ ei, int* __restrict__ ib) {
  int e = blockIdx.x * 256 + threadIdx.x;
  if (e < N_EDGES) atomicAdd(&ib[IHIST + ei[N_EDGES + e]], 1);
}

__global__ __launch_bounds__(1024) void k_scan(int* __restrict__ ib) {
  __shared__ int csum[1024];
  int t = threadIdx.x;
  const int CHUNK = (N_NODES + 1023) / 1024;
  int beg = t * CHUNK;
  int end = beg + CHUNK; if (end > N_NODES) end = N_NODES;
  int s = 0;
  for (int i = beg; i < end && i < N_NODES; ++i) s += ib[IHIST + i];
  csum[t] = s;
  __syncthreads();
  for (int off = 1; off < 1024; off <<= 1) {
    int v = (t >= off) ? csum[t - off] : 0;
    __syncthreads();
    csum[t] += v;
    __syncthreads();
  }
  int run = (t == 0) ? 0 : csum[t - 1];
  for (int i = beg; i < end && i < N_NODES; ++i) {
    ib[IROWPTR + i] = run;
    ib[ICUR + i] = run;
    run += ib[IHIST + i];
  }
  if (t == 1023) ib[IROWPTR + N_NODES] = run;
}

__global__ void k_scatter(const int* __restrict__ ei, int* __restrict__ ib) {
  int e = blockIdx.x * 256 + threadIdx.x;
  if (e < N_EDGES) {
    int pos = atomicAdd(&ib[ICUR + ei[N_EDGES + e]], 1);
    ib[IPERM + pos] = e;
  }
}

// -------- node projection via MFMA: [32 x 384] @ [Wq|Wkv] (576 cols) --------
__global__ __launch_bounds__(256) void k_node_proj_mfma(
    const ushort* __restrict__ sb, const float* __restrict__ rots, const float* __restrict__ trans,
    const ushort* __restrict__ wswz,
    const float* __restrict__ bq, const float* __restrict__ bkv,
    float* __restrict__ ws) {
  const int n0 = blockIdx.x * 32;
  const int tid = threadIdx.x;
  const int wave = tid >> 6, lane = tid & 63, quad = lane >> 4, l16 = lane & 15;
  const int rowhalf = wave & 1, thalf = wave >> 1;
  __shared__ __align__(16) bf16 pbuf[32][584];
  __shared__ float RmL[32][9], tvL[32][3];
  for (int i = tid; i < 32*9; i += 256) {
    int nl = i/9, j = i - nl*9; int nd = n0 + nl;
    RmL[nl][j] = (nd < N_NODES) ? rots[nd*9 + j] : 0.f;
  }
  for (int i = tid; i < 32*3; i += 256) {
    int nl = i/3, j = i - nl*3; int nd = n0 + nl;
    tvL[nl][j] = (nd < N_NODES) ? 0.1f * trans[nd*3 + j] : 0.f;
  }

  const int row = rowhalf*16 + l16;
  int nd = n0 + row;
  const int nclamp = (nd < N_NODES) ? nd : 0;
  f32x4 acc[18];
#pragma unroll
  for (int i = 0; i < 18; ++i) acc[i] = (f32x4){0.f, 0.f, 0.f, 0.f};
  const short8* bq8 = (const short8*)(wswz + WQS);
  const short8* bkv8 = (const short8*)(wswz + WKVS);
#pragma unroll 2
  for (int kt = 0; kt < 12; ++kt) {
    short8 av = *(const short8*)(sb + nclamp*384 + kt*32 + quad*8);
#pragma unroll
    for (int nt = 0; nt < 18; ++nt) {
      int g = thalf*18 + nt;
      short8 bv = (g < 9) ? bq8[(kt*9 + g)*64 + lane]
                          : bkv8[(kt*27 + (g - 9))*64 + lane];
      acc[nt] = __builtin_amdgcn_mfma_f32_16x16x32_bf16(av, bv, acc[nt], 0, 0, 0);
    }
  }
#pragma unroll
  for (int nt = 0; nt < 18; ++nt) {
    int gcol = (thalf*18 + nt)*16 + l16;
    float bias = (gcol < 144) ? bq[gcol] : bkv[gcol - 144];
#pragma unroll
    for (int r = 0; r < 4; ++r)
      pbuf[rowhalf*16 + quad*4 + r][gcol] = __float2bfloat16(acc[nt][r] + bias);
  }
  __syncthreads();

  bf16* qpb = (bf16*)(ws + OFF_QPTS);
  bf16* kpb = (bf16*)(ws + OFF_KPTS);
  bf16* vph = (bf16*)(ws + OFF_VPTSH);
  for (int i = tid; i < 32*192; i += 256) {
    int nl = i / 192, p = i - nl*192;
    int node = n0 + nl;
    if (node >= N_NODES) continue;
    float c0, c1, c2;
    if (p < 48) {
      c0 = __bfloat162float(pbuf[nl][p]);
      c1 = __bfloat162float(pbuf[nl][48 + p]);
      c2 = __bfloat162float(pbuf[nl][96 + p]);
    } else {
      int q = p - 48;
      c0 = __bfloat162float(pbuf[nl][144 + q]);
      c1 = __bfloat162float(pbuf[nl][288 + q]);
      c2 = __bfloat162float(pbuf[nl][432 + q]);
    }
    const float* Rm = RmL[nl];
    const float* tv = tvL[nl];
    float r0 = Rm[0]*c0 + Rm[1]*c1 + Rm[2]*c2 + tv[0];
    float r1 = Rm[3]*c0 + Rm[4]*c1 + Rm[5]*c2 + tv[1];
    float r2 = Rm[6]*c0 + Rm[7]*c1 + Rm[8]*c2 + tv[2];
    if (p < 48) {
      int base = node*144 + p*3;
      qpb[base]   = __float2bfloat16(r0);
      qpb[base+1] = __float2bfloat16(r1);
      qpb[base+2] = __float2bfloat16(r2);
    } else {
      int q = p - 48; int h = q / 12, idx = q % 12;
      if (idx < PQ) {
        int base = node*144 + (h*PQ + idx)*3;
        kpb[base]   = __float2bfloat16(r0);
        kpb[base+1] = __float2bfloat16(r1);
        kpb[base+2] = __float2bfloat16(r2);
      } else {
        int base = node*288 + (h*PV + (idx - PQ))*3;
        vph[base]   = __float2bfloat16(r0);
        vph[base+1] = __float2bfloat16(r1);
        vph[base+2] = __float2bfloat16(r2);
      }
    }
  }
}

// ---------------- fused edge logit via MFMA, M=64 tile, SORTED edges ----------------
// M=64 (one 16-row group per wave, acc[12]+accB+accW = 56 acc regs): keeps >=2 waves/SIMD.
// R4 post-mortem: M=128's 24x f32x4 accumulators pushed VGPR+AGPR past 256 -> 1 wave/SIMD
// (Occupancy 11.6%), latency-bound (MfmaUtil 7.4%). Reverted; sorted writes + Wb fusion kept.
// R7: confirmed — total 994.6 -> 909.3 us, logit no longer the top dispatch.
__global__ __launch_bounds__(256) void k_edge_logit_mfma(
    const ushort* __restrict__ sb, const float* __restrict__ zp, const int* __restrict__ ei,
    const float* __restrict__ mask,
    const ushort* __restrict__ wswz,
    const float* __restrict__ bw1, const float* __restrict__ bw2, const float* __restrict__ bw3,
    const float* __restrict__ bb, const float* __restrict__ hw,
    const ushort* __restrict__ qpb, const ushort* __restrict__ kpb,
    const int* __restrict__ ib,
    float* __restrict__ logit) {
  const int e0 = blockIdx.x * 64;
  const int tid = threadIdx.x;
  const int wave = tid >> 6, lane = tid & 63, quad = lane >> 4, l16 = lane & 15;
  __shared__ __align__(16) bf16 hbuf[64][200];   // 25.6 KB, rows strictly wave-owned
  __shared__ int seL[64], deL[64], eIdL[64];
  if (tid < 64) {
    int e = ib[IPERM + e0 + tid];
    eIdL[tid] = e; deL[tid] = ei[e]; seL[tid] = ei[N_EDGES + e];
  }
  __syncthreads();

  const int r0 = wave*16 + l16;
  const int es0 = seL[r0], ed0 = deL[r0], ez0 = eIdL[r0];

  f32x4 acc0[12];
#pragma unroll
  for (int i = 0; i < 12; ++i) acc0[i] = (f32x4){0.f, 0.f, 0.f, 0.f};
  f32x4 accB0 = (f32x4){0.f, 0.f, 0.f, 0.f};
  const short8* bw = (const short8*)(wswz + WW1S);
  const short8* bB8 = (const short8*)(wswz + WBS);
  // W1, K-range [0,384): s[src]
#pragma unroll 2
  for (int kt = 0; kt < 12; ++kt) {
    int k0 = kt*32 + quad*8;
    short8 a0 = *(const short8*)(sb + es0*384 + k0);
    const short8* bk = bw + (kt*12*64 + lane);
#pragma unroll
    for (int nt = 0; nt < 12; ++nt) {
      short8 bv = bk[nt*64];
      acc0[nt] = __builtin_amdgcn_mfma_f32_16x16x32_bf16(a0, bv, acc0[nt], 0, 0, 0);
    }
  }
  // W1, K-range [384,768): s[dst]
#pragma unroll 2
  for (int kt = 12; kt < 24; ++kt) {
    int k0 = (kt - 12)*32 + quad*8;
    short8 a0 = *(const short8*)(sb + ed0*384 + k0);
    const short8* bk = bw + (kt*12*64 + lane);
#pragma unroll
    for (int nt = 0; nt < 12; ++nt) {
      short8 bv = bk[nt*64];
      acc0[nt] = __builtin_amdgcn_mfma_f32_16x16x32_bf16(a0, bv, acc0[nt], 0, 0, 0);
    }
  }
  // W1, K-range [768,896): z  — fuse Wb (identical A fragments)
#pragma unroll 2
  for (int kt = 24; kt < 28; ++kt) {
    int k0 = (kt - 24)*32 + quad*8;
    short8 a0 = lda8f(zp, ez0*128 + k0);
    const short8* bk = bw + (kt*12*64 + lane);
#pragma unroll
    for (int nt = 0; nt < 12; ++nt) {
      short8 bv = bk[nt*64];
      acc0[nt] = __builtin_amdgcn_mfma_f32_16x16x32_bf16(a0, bv, acc0[nt], 0, 0, 0);
    }
    short8 bvB = bB8[(kt - 24)*64 + lane];
    accB0 = __builtin_amdgcn_mfma_f32_16x16x32_bf16(a0, bvB, accB0, 0, 0, 0);
  }
  // W1 epilogue (wave-owned rows; no barrier needed between stages)
#pragma unroll
  for (int nt = 0; nt < 12; ++nt) {
    float bcol = bw1[nt*16 + l16];
#pragma unroll
    for (int r = 0; r < 4; ++r)
      hbuf[wave*16 + quad*4 + r][nt*16 + l16] =
          __float2bfloat16(fmaxf(acc0[nt][r] + bcol, 0.f));
  }

  // W2
#pragma unroll
  for (int i = 0; i < 12; ++i) acc0[i] = (f32x4){0.f, 0.f, 0.f, 0.f};
  bw = (const short8*)(wswz + WW2S);
#pragma unroll
  for (int kt = 0; kt < 6; ++kt) {
    short8 a0 = *(const short8*)&hbuf[r0][kt*32 + quad*8];
    const short8* bk = bw + (kt*12*64 + lane);
#pragma unroll
    for (int nt = 0; nt < 12; ++nt) {
      short8 bv = bk[nt*64];
      acc0[nt] = __builtin_amdgcn_mfma_f32_16x16x32_bf16(a0, bv, acc0[nt], 0, 0, 0);
    }
  }
#pragma unroll
  for (int nt = 0; nt < 12; ++nt) {
    float bcol = bw2[nt*16 + l16];
#pragma unroll
    for (int r = 0; r < 4; ++r)
      hbuf[wave*16 + quad*4 + r][nt*16 + l16] =
          __float2bfloat16(fmaxf(acc0[nt][r] + bcol, 0.f));
  }

  // W3
  f32x4 accW0 = (f32x4){0.f, 0.f, 0.f, 0.f};
  const short8* b3 = (const short8*)(wswz + WW3S);
#pragma unroll
  for (int kt = 0; kt < 6; ++kt) {
    short8 a0 = *(const short8*)&hbuf[r0][kt*32 + quad*8];
    short8 bv = b3[kt*64 + lane];
    accW0 = __builtin_amdgcn_mfma_f32_16x16x32_bf16(a0, bv, accW0, 0, 0, 0);
  }

  if (l16 < 12) {
    const int h = l16;
    float hv = hw[h];
    float hws = logf(1.0f + expf(hv)) * 0.1360827634879543f;
    float b3c = bw3[h], bbc = bb[h];
#pragma unroll
    for (int r = 0; r < 4; ++r) {
      int eloc = wave*16 + quad*4 + r;
      int se = seL[eloc], de = deL[eloc];
      float v = (accW0[r] + b3c) * 0.041666666666666664f + 0.5773502691896258f * (accB0[r] + bbc);
      int qb = se*144 + h*12;
      int kb = de*144 + h*12;
      float pa = 0.f;
#pragma unroll
      for (int t3 = 0; t3 < 3; ++t3) {
        s16x4 qv = *(const s16x4*)(qpb + qb + t3*4);
        s16x4 kv = *(const s16x4*)(kpb + kb + t3*4);
#pragma unroll
        for (int u = 0; u < 4; ++u) {
          float d = bf((ushort)qv[u]) - bf((ushort)kv[u]);
          pa += d*d;
        }
      }
      v -= 0.5f * hws * pa;
      v += 100000.0f * (mask[de] * mask[se] - 1.0f);
      logit[(e0 + eloc)*12 + h] = v;   // sorted position
    }
  }
}

// ------- per-(node,head) softmax over contiguous sorted segments; no atomics -------
// Replaces k_amax + k_exp. In-place: logit -> normalized attention a.
__global__ void k_softmax(float* __restrict__ a, const int* __restrict__ ib) {
  int t = blockIdx.x * 256 + threadIdx.x;
  if (t >= N_NODES * 12) return;
  int n = t / 12, h = t - n*12;
  int b = ib[IROWPTR + n], e = ib[IROWPTR + n + 1];
  if (b == e) return;
  float m = -3.4e38f;
  for (int j = b; j < e; ++j) m = fmaxf(m, a[j*12 + h]);
  float s = 0.f;
  for (int j = b; j < e; ++j) {
    float ex = expf(a[j*12 + h] - m);
    s += ex;
    a[j*12 + h] = ex;
  }
  float inv = 1.f / (s + 1e-16f);
  for (int j = b; j < e; ++j) a[j*12 + h] *= inv;
}

// ------- fused edge accum via MFMA over SORTED edges + per-wave segmented scatter -------
// R7 restructure (accum was top dispatch: 294.6us, Occ 29.4% LDS-limited, MfmaUtil 7.8%,
// VALUBusy 20%, 64-deep serial scans on <=192 threads, ~12 barriers):
//  - per-wave private LDS chunks: hb + all stg sections wave-owned -> ONE __syncthreads
//  - LDS 53.2KB -> 30.5KB: 3 -> 5 blocks/CU (occupancy ceiling 62.5%)
//  - scans 64-deep -> 16-deep per wave, all 256 threads active
//  - o split into 2x96-col halves (stride 97); v_pts into 4x72-col chans (stride 76, vec)
// Extra atomics only at forced wave boundaries (bounded: <=3/col/block).
__global__ __launch_bounds__(256) void k_edge_accum_mfma(
    const ushort* __restrict__ sb, const float* __restrict__ zp, const int* __restrict__ ei,
    const ushort* __restrict__ wswz,
    const float* __restrict__ bv1, const float* __restrict__ bv2, const float* __restrict__ bv3,
    const float* __restrict__ bdz,
    const float* __restrict__ aS,
    const bf16* __restrict__ vph, const int* __restrict__ ib,
    float* __restrict__ acc_o, float* __restrict__ acc_p, float* __restrict__ acc_z) {
  const int p0 = blockIdx.x * 64;
  const int tid = threadIdx.x;
  const int wave = tid >> 6, lane = tid & 63, quad = lane >> 4, l16 = lane & 15;
  __shared__ __align__(16) unsigned char smem[4][6656];   // per-wave chunks, 26.0 KB
  __shared__ float awL[64][12];
  __shared__ int seL[64], deL[64], eIdL[64];
  bf16* hb = (bf16*)smem[wave];     // 16 x 200 bf16 (wave-local rows)
  float* stg = (float*)smem[wave];  // per-section layouts (wave-local rows)
  if (tid < 64) {
    int e = ib[IPERM + p0 + tid];
    eIdL[tid] = e;
    deL[tid] = ei[e];
    seL[tid] = ei[N_EDGES + e];
  }
  for (int i = tid; i < 64*12; i += 256)
    (&awL[0][0])[i] = aS[p0*12 + i];   // contiguous, already normalized
  __syncthreads();   // the ONLY barrier: seL/deL/eIdL + awL now visible to all waves

  const int arow = wave*16 + l16;
  const int edst = deL[arow];
  const int eid  = eIdL[arow];

  f32x4 acc[12];
#pragma unroll
  for (int i = 0; i < 12; ++i) acc[i] = (f32x4){0.f, 0.f, 0.f, 0.f};
  f32x4 apz[2];
  apz[0] = (f32x4){0.f, 0.f, 0.f, 0.f};
  apz[1] = (f32x4){0.f, 0.f, 0.f, 0.f};
  const short8* bw = (const short8*)(wswz + WV1S);
  const short8* bz = (const short8*)(wswz + WDZS);
  // V1, K-range [0,384): s[dst]
#pragma unroll 2
  for (int kt = 0; kt < 12; ++kt) {
    short8 av = *(const short8*)(sb + edst*384 + kt*32 + quad*8);
    const short8* bk = bw + (kt*12*64 + lane);
#pragma unroll
    for (int nt = 0; nt < 12; ++nt) {
      short8 bv = bk[nt*64];
      acc[nt] = __builtin_amdgcn_mfma_f32_16x16x32_bf16(av, bv, acc[nt], 0, 0, 0);
    }
  }
  // V1, K-range [384,512): z — fuse Wdz (identical A fragments)
#pragma unroll 2
  for (int kt = 12; kt < 16; ++kt) {
    int kz = (kt - 12)*32 + quad*8;
    short8 av = lda8f(zp, eid*128 + kz);
    const short8* bk = bw + (kt*12*64 + lane);
#pragma unroll
    for (int nt = 0; nt < 12; ++nt) {
      short8 bv = bk[nt*64];
      acc[nt] = __builtin_amdgcn_mfma_f32_16x16x32_bf16(av, bv, acc[nt], 0, 0, 0);
    }
#pragma unroll
    for (int nt = 0; nt < 2; ++nt) {
      short8 bvz = bz[((kt - 12)*2 + nt)*64 + lane];
      apz[nt] = __builtin_amdgcn_mfma_f32_16x16x32_bf16(av, bvz, apz[nt], 0, 0, 0);
    }
  }
  // V1 epilogue -> wave-local hb rows (in-order DS per wave; no barriers from here on)
#pragma unroll
  for (int nt = 0; nt < 12; ++nt) {
    float bcol = bv1[nt*16 + l16];
#pragma unroll
    for (int r = 0; r < 4; ++r)
      hb[(quad*4 + r)*200 + nt*16 + l16] =
          __float2bfloat16(fmaxf(acc[nt][r] + bcol, 0.f));
  }

  // V2
#pragma unroll
  for (int i = 0; i < 12; ++i) acc[i] = (f32x4){0.f, 0.f, 0.f, 0.f};
  bw = (const short8*)(wswz + WV2S);
#pragma unroll
  for (int kt = 0; kt < 6; ++kt) {
    short8 av = *(const short8*)&hb[l16*200 + kt*32 + quad*8];
    const short8* bk = bw + (kt*12*64 + lane);
#pragma unroll
    for (int nt = 0; nt < 12; ++nt) {
      short8 bv = bk[nt*64];
      acc[nt] = __builtin_amdgcn_mfma_f32_16x16x32_bf16(av, bv, acc[nt], 0, 0, 0);
    }
  }
#pragma unroll
  for (int nt = 0; nt < 12; ++nt) {
    float bcol = bv2[nt*16 + l16];
#pragma unroll
    for (int r = 0; r < 4; ++r)
      hb[(quad*4 + r)*200 + nt*16 + l16] =
          __float2bfloat16(fmaxf(acc[nt][r] + bcol, 0.f));
  }

  // V3
#pragma unroll
  for (int i = 0; i < 12; ++i) acc[i] = (f32x4){0.f, 0.f, 0.f, 0.f};
  bw = (const short8*)(wswz + WV3S);
#pragma unroll
  for (int kt = 0; kt < 6; ++kt) {
    short8 av = *(const short8*)&hb[l16*200 + kt*32 + quad*8];
    const short8* bk = bw + (kt*12*64 + lane);
#pragma unroll
    for (int nt = 0; nt < 12; ++nt) {
      short8 bv = bk[nt*64];
      acc[nt] = __builtin_amdgcn_mfma_f32_16x16x32_bf16(av, bv, acc[nt], 0, 0, 0);
    }
  }

  // ---- o-scatter: a*(h@Wv3+b), 2 col-halves of 96, stride 97, wave-local 16-row scans ----
#pragma unroll
  for (int half = 0; half < 2; ++half) {
#pragma unroll
    for (int nti = 0; nti < 6; ++nti) {
      int nt = half*6 + nti;
      int lc = nti*16 + l16;                 // local col in [0,96)
      float bcol = bv3[nt*16 + l16];
#pragma unroll
      for (int r = 0; r < 4; ++r) {
        int lr = quad*4 + r;
        stg[lr*97 + lc] = awL[wave*16 + lr][nt] * (acc[nt][r] + bcol);
      }
    }
    for (int c = lane; c < 96; c += 64) {
      float sum = 0.f;
#pragma unroll
      for (int lr = 0; lr < 16; ++lr) {
        int gr = wave*16 + lr;
        sum += stg[lr*97 + c];
        if (lr == 15 || seL[gr+1] != seL[gr]) {
          atomicAdd(&acc_o[seL[gr]*192 + half*96 + c], sum);
          sum = 0.f;
        }
      }
    }
  }

  // ---- z-scatter: a*(z@Wdz+b), 32 cols x 12 heads, stride 33 ----
  {
#pragma unroll
    for (int nt = 0; nt < 2; ++nt) {
      int c = nt*16 + l16;
      float bcol = bdz[c];
#pragma unroll
      for (int r = 0; r < 4; ++r) {
        int lr = quad*4 + r;
        stg[lr*33 + c] = apz[nt][r] + bcol;
      }
    }
    for (int p = lane; p < 384; p += 64) {
      int h = p >> 5, c = p & 31;
      float sum = 0.f;
#pragma unroll
      for (int lr = 0; lr < 16; ++lr) {
        int gr = wave*16 + lr;
        sum += awL[gr][h] * stg[lr*33 + c];
        if (lr == 15 || seL[gr+1] != seL[gr]) {
          atomicAdd(&acc_z[seL[gr]*384 + h*32 + c], sum);
          sum = 0.f;
        }
      }
    }
  }

  // ---- v_pts scatter: a*v_pts[dst], 4 channels of 72 cols, stride 76 (16B-aligned rows) ----
  for (int ch = 0; ch < 4; ++ch) {
    // fill: vectorized s16x4 gather (jj 4-aligned; h constant within each 4-group)
    for (int i = lane; i < 16*18; i += 64) {
      int lr = i / 18, g4 = i - lr*18;
      int jj = g4*4;
      int j = ch*72 + jj;
      int h = j / 24;
      int gr = wave*16 + lr;
      float aw = awL[gr][h];
      s16x4 vv = *(const s16x4*)(vph + deL[gr]*288 + j);
      f32x4 o;
      o[0] = aw * bf((ushort)vv[0]);
      o[1] = aw * bf((ushort)vv[1]);
      o[2] = aw * bf((ushort)vv[2]);
      o[3] = aw * bf((ushort)vv[3]);
      *(f32x4*)(stg + lr*76 + jj) = o;
    }
    for (int c = lane; c < 72; c += 64) {
      float sum = 0.f;
#pragma unroll
      for (int lr = 0; lr < 16; ++lr) {
        int gr = wave*16 + lr;
        sum += stg[lr*76 + c];
        if (lr == 15 || seL[gr+1] != seL[gr]) {
          atomicAdd(&acc_p[seL[gr]*288 + ch*72 + c], sum);
          sum = 0.f;
        }
      }
    }
  }
}

// -------- node output via MFMA: feats [32 x 960] @ Wo [960 x 384] --------
__global__ __launch_bounds__(256) void k_node_out_mfma(
    const float* __restrict__ rots, const float* __restrict__ trans,
    const ushort* __restrict__ wswz, const float* __restrict__ bo,
    const float* __restrict__ acc_o, const float* __restrict__ acc_p,
    const float* __restrict__ acc_z, float* __restrict__ out) {
  const int n0 = blockIdx.x * 32;
  const int tid = threadIdx.x;
  const int wave = tid >> 6, lane = tid & 63, quad = lane >> 4, l16 = lane & 15;
  __shared__ __align__(16) bf16 fbuf[32][968];
  __shared__ float RmL[32][9], tvL[32][3];
  for (int i = tid; i < 32*9; i += 256) {
    int nl = i/9, j = i - nl*9; int nd = n0 + nl;
    RmL[nl][j] = (nd < N_NODES) ? rots[nd*9 + j] : 0.f;
  }
  for (int i = tid; i < 32*3; i += 256) {
    int nl = i/3, j = i - nl*3; int nd = n0 + nl;
    tvL[nl][j] = (nd < N_NODES) ? 0.1f * trans[nd*3 + j] : 0.f;
  }
  __syncthreads();
  for (int i = tid; i < 32*192; i += 256) {
    int nl = i/192, c = i - nl*192; int nd = n0 + nl;
    fbuf[nl][c] = __float2bfloat16((nd < N_NODES) ? acc_o[nd*192 + c] : 0.f);
  }
  for (int i = tid; i < 32*96; i += 256) {
    int nl = i/96, pt = i - nl*96; int nd = n0 + nl;
    float r0 = 0.f, r1 = 0.f, r2 = 0.f, nm = 0.f;
    if (nd < N_NODES) {
      const float* Rm = RmL[nl];
      float v0 = acc_p[nd*288 + pt*3 + 0] - tvL[nl][0];
      float v1 = acc_p[nd*288 + pt*3 + 1] - tvL[nl][1];
      float v2 = acc_p[nd*288 + pt*3 + 2] - tvL[nl][2];
      r0 = Rm[0]*v0 + Rm[3]*v1 + Rm[6]*v2;
      r1 = Rm[1]*v0 + Rm[4]*v1 + Rm[7]*v2;
      r2 = Rm[2]*v0 + Rm[5]*v1 + Rm[8]*v2;
      nm = sqrtf(r0*r0 + r1*r1 + r2*r2 + 1e-8f);
    }
    fbuf[nl][192 + pt] = __float2bfloat16(r0);
    fbuf[nl][288 + pt] = __float2bfloat16(r1);
    fbuf[nl][384 + pt] = __float2bfloat16(r2);
    fbuf[nl][480 + pt] = __float2bfloat16(nm);
  }
  for (int i = tid; i < 32*384; i += 256) {
    int nl = i/384, c = i - nl*384; int nd = n0 + nl;
    fbuf[nl][576 + c] = __float2bfloat16((nd < N_NODES) ? acc_z[nd*384 + c] : 0.f);
  }
  __syncthreads();

  const int rowhalf = wave & 1, thalf = wave >> 1;
  f32x4 acc[12];
#pragma unroll
  for (int i = 0; i < 12; ++i) acc[i] = (f32x4){0.f, 0.f, 0.f, 0.f};
  const short8* bwo = (const short8*)(wswz + WOS);
#pragma unroll 2
  for (int kt = 0; kt < 30; ++kt) {
    short8 av = *(const short8*)&fbuf[rowhalf*16 + l16][kt*32 + quad*8];
#pragma unroll
    for (int nt = 0; nt < 12; ++nt) {
      short8 bv = bwo[(kt*24 + thalf*12 + nt)*64 + lane];
      acc[nt] = __builtin_amdgcn_mfma_f32_16x16x32_bf16(av, bv, acc[nt], 0, 0, 0);
    }
  }
#pragma unroll
  for (int nt = 0; nt < 12; ++nt) {
    int col = (thalf*12 + nt)*16 + l16;
    float bias = bo[col];
#pragma unroll
    for (int r = 0; r < 4; ++r) {
      int nd = n0 + rowhalf*16 + quad*4 + r;
      if (nd < N_NODES) out[nd*384 + col] = acc[nt][r] + bias;
    }
  }
}

extern "C" void kernel_launch(void* const* d_in, const int* in_sizes, int n_in,
                              void* d_out, int out_size, void* d_ws, size_t ws_size,
                              hipStream_t stream) {
  const float* s     = (const float*)d_in[0];
  const float* z     = (const float*)d_in[1];
  const int*   ei    = (const int*)d_in[2];
  const float* rots  = (const float*)d_in[3];
  const float* trans = (const float*)d_in[4];
  const float* mask  = (const float*)d_in[5];
  const float* Ww1 = (const float*)d_in[6];  const float* bw1 = (const float*)d_in[7];
  const float* Ww2 = (const float*)d_in[8];  const float* bw2 = (const float*)d_in[9];
  const float* Ww3 = (const float*)d_in[10]; const float* bw3 = (const float*)d_in[11];
  const float* Wv1 = (const float*)d_in[12]; const float* bv1 = (const float*)d_in[13];
  const float* Wv2 = (const float*)d_in[14]; const float* bv2 = (const float*)d_in[15];
  const float* Wv3 = (const float*)d_in[16]; const float* bv3 = (const float*)d_in[17];
  const float* Wq  = (const float*)d_in[18]; const float* bq  = (const float*)d_in[19];
  const float* Wkv = (const float*)d_in[20]; const float* bkv = (const float*)d_in[21];
  const float* Wb  = (const float*)d_in[22]; const float* bb  = (const float*)d_in[23];
  const float* Wdz = (const float*)d_in[24]; const float* bdz = (const float*)d_in[25];
  const float* Wo  = (const float*)d_in[26]; const float* bo  = (const float*)d_in[27];
  const float* hw  = (const float*)d_in[28];
  float* ws = (float*)d_ws;
  ushort* wswz = (ushort*)(ws + FP32_TOTAL);
  int* ib = (int*)(wswz + SWZ_TOTAL);
  float* out = (float*)d_out;
  ushort* sb = (ushort*)(ws + OFF_SB);

  const int ntot = N_NODES * (192 + 288 + 384);
  k_init<<<(ntot + 255)/256, 256, 0, stream>>>(ws, ib);
  k_cast_s<<<(N_NODES*CS/4 + 255)/256, 256, 0, stream>>>(s, sb);

  SwzArgs A;
  const float* srcs[11] = {Ww1, Ww2, Ww3, Wb, Wv1, Wv2, Wv3, Wdz, Wq, Wkv, Wo};
  int offs[11]   = {WW1S, WW2S, WW3S, WBS, WV1S, WV2S, WV3S, WDZS, WQS, WKVS, WOS};
  int Ks[11]     = {896, 192, 192, 128, 512, 192, 192, 128, 384, 384, 960};
  int Nreals[11] = {192, 192, 12, 12, 192, 192, 192, 32, 144, 432, 384};
  int NTs[11]    = {12, 12, 1, 1, 12, 12, 12, 2, 9, 27, 24};
  int cum = 0;
  for (int m = 0; m < 11; ++m) {
    A.src[m] = srcs[m]; A.off[m] = offs[m]; A.start[m] = cum;
    A.Nreal[m] = Nreals[m]; A.NT[m] = NTs[m];
    cum += (Ks[m]/32) * NTs[m] * 512;
  }
  k_swz_all<<<(cum + 255)/256, 256, 0, stream>>>(A, wswz, cum);

  // sort first: logits are produced in sorted order
  k_hist<<<(N_EDGES + 255)/256, 256, 0, stream>>>(ei, ib);
  k_scan<<<1, 1024, 0, stream>>>(ib);
  k_scatter<<<(N_EDGES + 255)/256, 256, 0, stream>>>(ei, ib);

  k_node_proj_mfma<<<(N_NODES + 31)/32, 256, 0, stream>>>(
      sb, rots, trans, wswz, bq, bkv, ws);

  k_edge_logit_mfma<<<N_EDGES/64, 256, 0, stream>>>(
      sb, z, ei, mask, wswz,
      bw1, bw2, bw3, bb, hw,
      (const ushort*)(ws + OFF_QPTS), (const ushort*)(ws + OFF_KPTS),
      ib, ws + OFF_LOGIT);

  k_softmax<<<(N_NODES*12 + 255)/256, 256, 0, stream>>>(ws + OFF_LOGIT, ib);

  k_edge_accum_mfma<<<N_EDGES/64, 256, 0, stream>>>(
      sb, z, ei, wswz,
      bv1, bv2, bv3, bdz,
      ws + OFF_LOGIT,
      (const bf16*)(ws + OFF_VPTSH), ib,
      ws + OFF_ACCO, ws + OFF_ACCP, ws + OFF_ACCZ);

  k_node_out_mfma<<<(N_NODES + 31)/32, 256, 0, stream>>>(
      rots, trans, wswz, bo,
      ws + OFF_ACCO, ws + OFF_ACCP, ws + OFF_ACCZ, out);
}

// Round 14
// 784.988 us; speedup vs baseline: 1.3515x; 1.3515x over previous
//
#include <hip/hip_runtime.h>
#include <hip/hip_bf16.h>
#include <math.h>

#define N_NODES 10000
#define N_EDGES 160000
#define CS 384
#define CZ 128
#define CH 192
#define NH 12
#define PQ 4
#define PV 8

typedef __hip_bfloat16 bf16;
typedef unsigned short ushort;
typedef __attribute__((ext_vector_type(8))) short short8;
typedef __attribute__((ext_vector_type(4))) short s16x4;
typedef __attribute__((ext_vector_type(4))) float f32x4;

__device__ __forceinline__ ushort cvt1(float f) {
  bf16 h = __float2bfloat16(f);
  return __builtin_bit_cast(unsigned short, h);
}
// fp32 -> bf16x8 fragment with guaranteed dwordx4 loads (idx 8-aligned)
// R10 audit: r[7] must read b[3] (f32x4 has 4 elems) — a round-9 resubmission typo had b[7].
__device__ __forceinline__ short8 lda8f(const float* p, int idx) {
  const f32x4* q = (const f32x4*)(p + idx);
  f32x4 a = q[0], b = q[1];
  short8 r;
  r[0] = (short)cvt1(a[0]); r[1] = (short)cvt1(a[1]);
  r[2] = (short)cvt1(a[2]); r[3] = (short)cvt1(a[3]);
  r[4] = (short)cvt1(b[0]); r[5] = (short)cvt1(b[1]);
  r[6] = (short)cvt1(b[2]); r[7] = (short)cvt1(b[3]);
  return r;
}
__device__ __forceinline__ float bf(ushort u) {
  return __bfloat162float(__builtin_bit_cast(bf16, u));
}

// ---- workspace layout (float offsets) ----
#define OFF_QPTS   0                              // N*144 bf16 (N*72 slots)
#define OFF_KPTS   (OFF_QPTS + N_NODES*72)        // N*144 bf16
#define OFF_VPTSH  (OFF_KPTS + N_NODES*72)        // N*288 bf16
#define OFF_SB     (OFF_VPTSH + N_NODES*144)      // N*384 bf16 (s pre-cast)
#define OFF_LOGIT  (OFF_SB + N_NODES*192)         // E*12 fp32 SORTED (becomes a after k_softmax)
#define OFF_AMAX   (OFF_LOGIT + N_EDGES*12)       // unused (kept for layout stability)
#define OFF_DENOM  (OFF_AMAX + N_NODES*12)        // unused
#define OFF_ACCO   (OFF_DENOM + N_NODES*12)       // N*192
#define OFF_ACCP   (OFF_ACCO + N_NODES*192)       // N*288
#define OFF_ACCZ   (OFF_ACCP + N_NODES*288)       // N*384 (holds sp_src/sp_dst bf16 until
                                                  //        k_zero_accz runs after logit)
#define FP32_TOTAL (OFF_ACCZ + N_NODES*384)

// sp (per-node W1 halves, bf16) live in the ACCZ region until accum needs it
#define SP_SRC_US  0                              // ushort offset within ACCZ region
#define SP_DST_US  (N_NODES*192)                  // 1.92M ushorts each; region holds 7.68M

// ---- swizzled weights (ushort offsets after FP32 region) ----
#define WW1S 0
#define WW2S 172032
#define WW3S 208896
#define WBS  211968
#define WV1S 214016
#define WV2S 312320
#define WV3S 349184
#define WDZS 386048
#define WQS  390144
#define WKVS 445440
#define WOS  611328
#define SWZ_TOTAL 979968

// ---- int region ----
#define IHIST   0
#define ICUR    10000
#define IROWPTR 20000
#define IPERM   30016

__global__ void k_init(float* __restrict__ ws, int* __restrict__ ib) {
  int idx = blockIdx.x * blockDim.x + threadIdx.x;
  const int ntot = N_NODES * (192 + 288);   // ACCO + ACCP only; ACCZ zeroed after logit
  if (idx < ntot) ws[OFF_ACCO + idx] = 0.0f;
  if (idx < N_NODES) ib[IHIST + idx] = 0;
}

__global__ void k_zero_accz(float* __restrict__ ws) {
  int idx = blockIdx.x * blockDim.x + threadIdx.x;
  if (idx < N_NODES*384) ws[OFF_ACCZ + idx] = 0.0f;
}

__global__ void k_cast_s(const float* __restrict__ s, ushort* __restrict__ sb) {
  int i = (blockIdx.x * 256 + threadIdx.x) * 4;
  if (i + 3 < N_NODES*CS) {
    f32x4 v = *(const f32x4*)(s + i);
    sb[i]   = cvt1(v[0]); sb[i+1] = cvt1(v[1]);
    sb[i+2] = cvt1(v[2]); sb[i+3] = cvt1(v[3]);
  }
}

// -------- merged weight swizzle (fp32 src -> bf16 B-fragment order), 11 matrices --------
struct SwzArgs {
  const float* src[11];
  int off[11], start[11], Nreal[11], NT[11];
};
__global__ void k_swz_all(SwzArgs A, ushort* __restrict__ dst, int grand) {
  int tid = blockIdx.x * blockDim.x + threadIdx.x;
  if (tid >= grand) return;
  int m = 0;
  while (m < 10 && tid >= A.start[m+1]) ++m;
  int t = tid - A.start[m];
  int j = t & 7, lane = (t >> 3) & 63, t2 = t >> 9;
  int nt = t2 % A.NT[m], kt = t2 / A.NT[m];
  int k = kt*32 + (lane >> 4)*8 + j;
  int n = nt*16 + (lane & 15);
  dst[A.off[m] + t] = (n < A.Nreal[m]) ? cvt1(A.src[m][k*A.Nreal[m] + n]) : (ushort)0;
}

// -------- counting sort by src --------
__global__ void k_hist(const int* __restrict__ ei, int* __restrict__ ib) {
  int e = blockIdx.x * 256 + threadIdx.x;
  if (e < N_EDGES) atomicAdd(&ib[IHIST + ei[N_EDGES + e]], 1);
}

__global__ __launch_bounds__(1024) void k_scan(int* __restrict__ ib) {
  __shared__ int csum[1024];
  int t = threadIdx.x;
  const int CHUNK = (N_NODES + 1023) / 1024;
  int beg = t * CHUNK;
  int end = beg + CHUNK; if (end > N_NODES) end = N_NODES;
  int s = 0;
  for (int i = beg; i < end && i < N_NODES; ++i) s += ib[IHIST + i];
  csum[t] = s;
  __syncthreads();
  for (int off = 1; off < 1024; off <<= 1) {
    int v = (t >= off) ? csum[t - off] : 0;
    __syncthreads();
    csum[t] += v;
    __syncthreads();
  }
  int run = (t == 0) ? 0 : csum[t - 1];
  for (int i = beg; i < end && i < N_NODES; ++i) {
    ib[IROWPTR + i] = run;
    ib[ICUR + i] = run;
    run += ib[IHIST + i];
  }
  if (t == 1023) ib[IROWPTR + N_NODES] = run;
}

__global__ void k_scatter(const int* __restrict__ ei, int* __restrict__ ib) {
  int e = blockIdx.x * 256 + threadIdx.x;
  if (e < N_EDGES) {
    int pos = atomicAdd(&ib[ICUR + ei[N_EDGES + e]], 1);
    ib[IPERM + pos] = e;
  }
}

// -------- per-node W1 halves: sp_src = s@W1[0:384], sp_dst = s@W1[384:768] (bf16, no bias) --------
// Reuses the existing W1 swizzle at kt 0..11 (src) / 12..23 (dst). Output into ACCZ region.
__global__ __launch_bounds__(256) void k_sp(
    const ushort* __restrict__ sb, const ushort* __restrict__ wswz,
    ushort* __restrict__ sp) {
  const int n0 = blockIdx.x * 32;
  const int tid = threadIdx.x;
  const int wave = tid >> 6, lane = tid & 63, quad = lane >> 4, l16 = lane & 15;
  const int rowhalf = wave & 1, part = wave >> 1;   // part 0 = src half, 1 = dst half
  const int row = rowhalf*16 + l16;
  int nd = n0 + row;
  const int nclamp = (nd < N_NODES) ? nd : 0;
  f32x4 acc[12];
#pragma unroll
  for (int i = 0; i < 12; ++i) acc[i] = (f32x4){0.f, 0.f, 0.f, 0.f};
  const short8* bw = (const short8*)(wswz + WW1S);
#pragma unroll 2
  for (int kt = 0; kt < 12; ++kt) {
    short8 av = *(const short8*)(sb + nclamp*384 + kt*32 + quad*8);
    const short8* bk = bw + ((part*12 + kt)*12*64 + lane);
#pragma unroll
    for (int nt = 0; nt < 12; ++nt) {
      short8 bv = bk[nt*64];
      acc[nt] = __builtin_amdgcn_mfma_f32_16x16x32_bf16(av, bv, acc[nt], 0, 0, 0);
    }
  }
  ushort* dst = sp + (part ? SP_DST_US : SP_SRC_US);
#pragma unroll
  for (int nt = 0; nt < 12; ++nt) {
    int col = nt*16 + l16;
#pragma unroll
    for (int r = 0; r < 4; ++r) {
      int node = n0 + rowhalf*16 + quad*4 + r;
      if (node < N_NODES) dst[node*192 + col] = cvt1(acc[nt][r]);
    }
  }
}

// -------- node projection via MFMA: [32 x 384] @ [Wq|Wkv] (576 cols) --------
__global__ __launch_bounds__(256) void k_node_proj_mfma(
    const ushort* __restrict__ sb, const float* __restrict__ rots, const float* __restrict__ trans,
    const ushort* __restrict__ wswz,
    const float* __restrict__ bq, const float* __restrict__ bkv,
    float* __restrict__ ws) {
  const int n0 = blockIdx.x * 32;
  const int tid = threadIdx.x;
  const int wave = tid >> 6, lane = tid & 63, quad = lane >> 4, l16 = lane & 15;
  const int rowhalf = wave & 1, thalf = wave >> 1;
  __shared__ __align__(16) bf16 pbuf[32][584];
  __shared__ float RmL[32][9], tvL[32][3];
  for (int i = tid; i < 32*9; i += 256) {
    int nl = i/9, j = i - nl*9; int nd = n0 + nl;
    RmL[nl][j] = (nd < N_NODES) ? rots[nd*9 + j] : 0.f;
  }
  for (int i = tid; i < 32*3; i += 256) {
    int nl = i/3, j = i - nl*3; int nd = n0 + nl;
    tvL[nl][j] = (nd < N_NODES) ? 0.1f * trans[nd*3 + j] : 0.f;
  }

  const int row = rowhalf*16 + l16;
  int nd = n0 + row;
  const int nclamp = (nd < N_NODES) ? nd : 0;
  f32x4 acc[18];
#pragma unroll
  for (int i = 0; i < 18; ++i) acc[i] = (f32x4){0.f, 0.f, 0.f, 0.f};
  const short8* bq8 = (const short8*)(wswz + WQS);
  const short8* bkv8 = (const short8*)(wswz + WKVS);
#pragma unroll 2
  for (int kt = 0; kt < 12; ++kt) {
    short8 av = *(const short8*)(sb + nclamp*384 + kt*32 + quad*8);
#pragma unroll
    for (int nt = 0; nt < 18; ++nt) {
      int g = thalf*18 + nt;
      short8 bv = (g < 9) ? bq8[(kt*9 + g)*64 + lane]
                          : bkv8[(kt*27 + (g - 9))*64 + lane];
      acc[nt] = __builtin_amdgcn_mfma_f32_16x16x32_bf16(av, bv, acc[nt], 0, 0, 0);
    }
  }
#pragma unroll
  for (int nt = 0; nt < 18; ++nt) {
    int gcol = (thalf*18 + nt)*16 + l16;
    float bias = (gcol < 144) ? bq[gcol] : bkv[gcol - 144];
#pragma unroll
    for (int r = 0; r < 4; ++r)
      pbuf[rowhalf*16 + quad*4 + r][gcol] = __float2bfloat16(acc[nt][r] + bias);
  }
  __syncthreads();

  bf16* qpb = (bf16*)(ws + OFF_QPTS);
  bf16* kpb = (bf16*)(ws + OFF_KPTS);
  bf16* vph = (bf16*)(ws + OFF_VPTSH);
  for (int i = tid; i < 32*192; i += 256) {
    int nl = i / 192, p = i - nl*192;
    int node = n0 + nl;
    if (node >= N_NODES) continue;
    float c0, c1, c2;
    if (p < 48) {
      c0 = __bfloat162float(pbuf[nl][p]);
      c1 = __bfloat162float(pbuf[nl][48 + p]);
      c2 = __bfloat162float(pbuf[nl][96 + p]);
    } else {
      int q = p - 48;
      c0 = __bfloat162float(pbuf[nl][144 + q]);
      c1 = __bfloat162float(pbuf[nl][288 + q]);
      c2 = __bfloat162float(pbuf[nl][432 + q]);
    }
    const float* Rm = RmL[nl];
    const float* tv = tvL[nl];
    float r0 = Rm[0]*c0 + Rm[1]*c1 + Rm[2]*c2 + tv[0];
    float r1 = Rm[3]*c0 + Rm[4]*c1 + Rm[5]*c2 + tv[1];
    float r2 = Rm[6]*c0 + Rm[7]*c1 + Rm[8]*c2 + tv[2];
    if (p < 48) {
      int base = node*144 + p*3;
      qpb[base]   = __float2bfloat16(r0);
      qpb[base+1] = __float2bfloat16(r1);
      qpb[base+2] = __float2bfloat16(r2);
    } else {
      int q = p - 48; int h = q / 12, idx = q % 12;
      if (idx < PQ) {
        int base = node*144 + (h*PQ + idx)*3;
        kpb[base]   = __float2bfloat16(r0);
        kpb[base+1] = __float2bfloat16(r1);
        kpb[base+2] = __float2bfloat16(r2);
      } else {
        int base = node*288 + (h*PV + (idx - PQ))*3;
        vph[base]   = __float2bfloat16(r0);
        vph[base+1] = __float2bfloat16(r1);
        vph[base+2] = __float2bfloat16(r2);
      }
    }
  }
}

// ---------------- fused edge logit via MFMA, M=64 tile, SORTED edges ----------------
// R8: W1 src/dst halves hoisted to per-node sp (k_sp) — K-loop 28 kt -> 4 kt (z only),
// node contributions added in the epilogue as gathered bf16 (384B/edge/side vs 768B
// A-fragment gathers). Wb stays fused in the z loop. Sorted writes kept.
__global__ __launch_bounds__(256) void k_edge_logit_mfma(
    const ushort* __restrict__ sb, const float* __restrict__ zp, const int* __restrict__ ei,
    const float* __restrict__ mask,
    const ushort* __restrict__ wswz,
    const float* __restrict__ bw1, const float* __restrict__ bw2, const float* __restrict__ bw3,
    const float* __restrict__ bb, const float* __restrict__ hw,
    const ushort* __restrict__ qpb, const ushort* __restrict__ kpb,
    const ushort* __restrict__ sps, const ushort* __restrict__ spd,
    const int* __restrict__ ib,
    float* __restrict__ logit) {
  const int e0 = blockIdx.x * 64;
  const int tid = threadIdx.x;
  const int wave = tid >> 6, lane = tid & 63, quad = lane >> 4, l16 = lane & 15;
  __shared__ __align__(16) bf16 hbuf[64][200];   // 25.6 KB, rows strictly wave-owned
  __shared__ int seL[64], deL[64], eIdL[64];
  if (tid < 64) {
    int e = ib[IPERM + e0 + tid];
    eIdL[tid] = e; deL[tid] = ei[e]; seL[tid] = ei[N_EDGES + e];
  }
  __syncthreads();

  const int r0 = wave*16 + l16;
  const int ez0 = eIdL[r0];

  f32x4 acc0[12];
#pragma unroll
  for (int i = 0; i < 12; ++i) acc0[i] = (f32x4){0.f, 0.f, 0.f, 0.f};
  f32x4 accB0 = (f32x4){0.f, 0.f, 0.f, 0.f};
  const short8* bw = (const short8*)(wswz + WW1S);
  const short8* bB8 = (const short8*)(wswz + WBS);
  // W1, z-part only (global K 768..896 = swizzled kt 24..27) — fuse Wb (identical A)
#pragma unroll 2
  for (int kt = 0; kt < 4; ++kt) {
    int k0 = kt*32 + quad*8;
    short8 a0 = lda8f(zp, ez0*128 + k0);
    const short8* bk = bw + ((24 + kt)*12*64 + lane);
#pragma unroll
    for (int nt = 0; nt < 12; ++nt) {
      short8 bv = bk[nt*64];
      acc0[nt] = __builtin_amdgcn_mfma_f32_16x16x32_bf16(a0, bv, acc0[nt], 0, 0, 0);
    }
    short8 bvB = bB8[kt*64 + lane];
    accB0 = __builtin_amdgcn_mfma_f32_16x16x32_bf16(a0, bvB, accB0, 0, 0, 0);
  }
  // W1 epilogue: add per-node sp halves (gathered bf16) + bias, relu, store
#pragma unroll
  for (int nt = 0; nt < 12; ++nt) {
    int col = nt*16 + l16;
    float bcol = bw1[col];
#pragma unroll
    for (int r = 0; r < 4; ++r) {
      int row = wave*16 + quad*4 + r;
      float v = acc0[nt][r] + bcol
              + bf(sps[seL[row]*192 + col])
              + bf(spd[deL[row]*192 + col]);
      hbuf[row][col] = __float2bfloat16(fmaxf(v, 0.f));
    }
  }

  // W2
#pragma unroll
  for (int i = 0; i < 12; ++i) acc0[i] = (f32x4){0.f, 0.f, 0.f, 0.f};
  bw = (const short8*)(wswz + WW2S);
#pragma unroll
  for (int kt = 0; kt < 6; ++kt) {
    short8 a0 = *(const short8*)&hbuf[r0][kt*32 + quad*8];
    const short8* bk = bw + (kt*12*64 + lane);
#pragma unroll
    for (int nt = 0; nt < 12; ++nt) {
      short8 bv = bk[nt*64];
      acc0[nt] = __builtin_amdgcn_mfma_f32_16x16x32_bf16(a0, bv, acc0[nt], 0, 0, 0);
    }
  }
#pragma unroll
  for (int nt = 0; nt < 12; ++nt) {
    float bcol = bw2[nt*16 + l16];
#pragma unroll
    for (int r = 0; r < 4; ++r)
      hbuf[wave*16 + quad*4 + r][nt*16 + l16] =
          __float2bfloat16(fmaxf(acc0[nt][r] + bcol, 0.f));
  }

  // W3
  f32x4 accW0 = (f32x4){0.f, 0.f, 0.f, 0.f};
  const short8* b3 = (const short8*)(wswz + WW3S);
#pragma unroll
  for (int kt = 0; kt < 6; ++kt) {
    short8 a0 = *(const short8*)&hbuf[r0][kt*32 + quad*8];
    short8 bv = b3[kt*64 + lane];
    accW0 = __builtin_amdgcn_mfma_f32_16x16x32_bf16(a0, bv, accW0, 0, 0, 0);
  }

  if (l16 < 12) {
    const int h = l16;
    float hv = hw[h];
    float hws = logf(1.0f + expf(hv)) * 0.1360827634879543f;
    float b3c = bw3[h], bbc = bb[h];
#pragma unroll
    for (int r = 0; r < 4; ++r) {
      int eloc = wave*16 + quad*4 + r;
      int se = seL[eloc], de = deL[eloc];
      float v = (accW0[r] + b3c) * 0.041666666666666664f + 0.5773502691896258f * (accB0[r] + bbc);
      int qb = se*144 + h*12;
      int kb = de*144 + h*12;
      float pa = 0.f;
#pragma unroll
      for (int t3 = 0; t3 < 3; ++t3) {
        s16x4 qv = *(const s16x4*)(qpb + qb + t3*4);
        s16x4 kv = *(const s16x4*)(kpb + kb + t3*4);
#pragma unroll
        for (int u = 0; u < 4; ++u) {
          float d = bf((ushort)qv[u]) - bf((ushort)kv[u]);
          pa += d*d;
        }
      }
      v -= 0.5f * hws * pa;
      v += 100000.0f * (mask[de] * mask[se] - 1.0f);
      logit[(e0 + eloc)*12 + h] = v;   // sorted position
    }
  }
}

// ------- per-(node,head) softmax over contiguous sorted segments; no atomics -------
__global__ void k_softmax(float* __restrict__ a, const int* __restrict__ ib) {
  int t = blockIdx.x * 256 + threadIdx.x;
  if (t >= N_NODES * 12) return;
  int n = t / 12, h = t - n*12;
  int b = ib[IROWPTR + n], e = ib[IROWPTR + n + 1];
  if (b == e) return;
  float m = -3.4e38f;
  for (int j = b; j < e; ++j) m = fmaxf(m, a[j*12 + h]);
  float s = 0.f;
  for (int j = b; j < e; ++j) {
    float ex = expf(a[j*12 + h] - m);
    s += ex;
    a[j*12 + h] = ex;
  }
  float inv = 1.f / (s + 1e-16f);
  for (int j = b; j < e; ++j) a[j*12 + h] *= inv;
}

// ------- fused edge accum via MFMA over SORTED edges + segmented scatter -------
// R8 post-mortem: wave-private-scan variant REGRESSED 294.6 -> 441.5us (occupancy did NOT
// rise with LDS cut — limiter isn't LDS; extra atomics + longer per-wave serial chains
// dominated, VALUBusy 20 -> 10.6). Reverted to the R7-measured block-cooperative version.
__global__ __launch_bounds__(256) void k_edge_accum_mfma(
    const ushort* __restrict__ sb, const float* __restrict__ zp, const int* __restrict__ ei,
    const ushort* __restrict__ wswz,
    const float* __restrict__ bv1, const float* __restrict__ bv2, const float* __restrict__ bv3,
    const float* __restrict__ bdz,
    const float* __restrict__ aS,
    const bf16* __restrict__ vph, const int* __restrict__ ib,
    float* __restrict__ acc_o, float* __restrict__ acc_p, float* __restrict__ acc_z) {
  const int p0 = blockIdx.x * 64;
  const int tid = threadIdx.x;
  const int wave = tid >> 6, lane = tid & 63, quad = lane >> 4, l16 = lane & 15;
  __shared__ __align__(16) unsigned char smem[64*193*4];
  __shared__ float awL[64][12];
  __shared__ int seL[64], deL[64], eIdL[64];
  bf16* hb = (bf16*)smem;
  float* stg = (float*)smem;
  if (tid < 64) {
    int e = ib[IPERM + p0 + tid];
    eIdL[tid] = e;
    deL[tid] = ei[e];
    seL[tid] = ei[N_EDGES + e];
  }
  __syncthreads();
  for (int i = tid; i < 64*12; i += 256)
    (&awL[0][0])[i] = aS[p0*12 + i];   // contiguous, already normalized

  const int arow = wave*16 + l16;
  const int edst = deL[arow];
  const int eid  = eIdL[arow];

  f32x4 acc[12];
#pragma unroll
  for (int i = 0; i < 12; ++i) acc[i] = (f32x4){0.f, 0.f, 0.f, 0.f};
  f32x4 apz[2];
  apz[0] = (f32x4){0.f, 0.f, 0.f, 0.f};
  apz[1] = (f32x4){0.f, 0.f, 0.f, 0.f};
  const short8* bw = (const short8*)(wswz + WV1S);
  const short8* bz = (const short8*)(wswz + WDZS);
  // V1, K-range [0,384): s[dst]
#pragma unroll 2
  for (int kt = 0; kt < 12; ++kt) {
    short8 av = *(const short8*)(sb + edst*384 + kt*32 + quad*8);
    const short8* bk = bw + (kt*12*64 + lane);
#pragma unroll
    for (int nt = 0; nt < 12; ++nt) {
      short8 bv = bk[nt*64];
      acc[nt] = __builtin_amdgcn_mfma_f32_16x16x32_bf16(av, bv, acc[nt], 0, 0, 0);
    }
  }
  // V1, K-range [384,512): z — fuse Wdz (identical A fragments)
#pragma unroll 2
  for (int kt = 12; kt < 16; ++kt) {
    int kz = (kt - 12)*32 + quad*8;
    short8 av = lda8f(zp, eid*128 + kz);
    const short8* bk = bw + (kt*12*64 + lane);
#pragma unroll
    for (int nt = 0; nt < 12; ++nt) {
      short8 bv = bk[nt*64];
      acc[nt] = __builtin_amdgcn_mfma_f32_16x16x32_bf16(av, bv, acc[nt], 0, 0, 0);
    }
#pragma unroll
    for (int nt = 0; nt < 2; ++nt) {
      short8 bvz = bz[((kt - 12)*2 + nt)*64 + lane];
      apz[nt] = __builtin_amdgcn_mfma_f32_16x16x32_bf16(av, bvz, apz[nt], 0, 0, 0);
    }
  }
  // V1 epilogue (hb rows are wave-owned; no cross-wave barrier needed until stg)
#pragma unroll
  for (int nt = 0; nt < 12; ++nt) {
    float bcol = bv1[nt*16 + l16];
#pragma unroll
    for (int r = 0; r < 4; ++r)
      hb[(wave*16 + quad*4 + r)*200 + nt*16 + l16] =
          __float2bfloat16(fmaxf(acc[nt][r] + bcol, 0.f));
  }

  // V2
#pragma unroll
  for (int i = 0; i < 12; ++i) acc[i] = (f32x4){0.f, 0.f, 0.f, 0.f};
  bw = (const short8*)(wswz + WV2S);
#pragma unroll
  for (int kt = 0; kt < 6; ++kt) {
    short8 av = *(const short8*)&hb[(wave*16 + l16)*200 + kt*32 + quad*8];
    const short8* bk = bw + (kt*12*64 + lane);
#pragma unroll
    for (int nt = 0; nt < 12; ++nt) {
      short8 bv = bk[nt*64];
      acc[nt] = __builtin_amdgcn_mfma_f32_16x16x32_bf16(av, bv, acc[nt], 0, 0, 0);
    }
  }
#pragma unroll
  for (int nt = 0; nt < 12; ++nt) {
    float bcol = bv2[nt*16 + l16];
#pragma unroll
    for (int r = 0; r < 4; ++r)
      hb[(wave*16 + quad*4 + r)*200 + nt*16 + l16] =
          __float2bfloat16(fmaxf(acc[nt][r] + bcol, 0.f));
  }

  // V3
#pragma unroll
  for (int i = 0; i < 12; ++i) acc[i] = (f32x4){0.f, 0.f, 0.f, 0.f};
  bw = (const short8*)(wswz + WV3S);
#pragma unroll
  for (int kt = 0; kt < 6; ++kt) {
    short8 av = *(const short8*)&hb[(wave*16 + l16)*200 + kt*32 + quad*8];
    const short8* bk = bw + (kt*12*64 + lane);
#pragma unroll
    for (int nt = 0; nt < 12; ++nt) {
      short8 bv = bk[nt*64];
      acc[nt] = __builtin_amdgcn_mfma_f32_16x16x32_bf16(av, bv, acc[nt], 0, 0, 0);
    }
  }
  __syncthreads();   // hb (all waves) dead; stg aliasing + awL cross-wave reads begin

#pragma unroll
  for (int nt = 0; nt < 12; ++nt) {
    int col = nt*16 + l16;
    float bcol = bv3[col];
#pragma unroll
    for (int r = 0; r < 4; ++r) {
      int eloc = wave*16 + quad*4 + r;
      stg[eloc*193 + col] = awL[eloc][nt] * (acc[nt][r] + bcol);
    }
  }
  __syncthreads();
  for (int c = tid; c < 192; c += 256) {
    float sum = 0.f;
    for (int r = 0; r < 64; ++r) {
      sum += stg[r*193 + c];
      if (r == 63 || seL[r+1] != seL[r]) {
        atomicAdd(&acc_o[seL[r]*192 + c], sum);
        sum = 0.f;
      }
    }
  }
  __syncthreads();

#pragma unroll
  for (int nt = 0; nt < 2; ++nt) {
    int c = nt*16 + l16;
    float bcol = bdz[c];
#pragma unroll
    for (int r = 0; r < 4; ++r) {
      int eloc = wave*16 + quad*4 + r;
      stg[eloc*33 + c] = apz[nt][r] + bcol;
    }
  }
  __syncthreads();
  for (int p = tid; p < 384; p += 256) {
    int h = p >> 5, c = p & 31;
    float sum = 0.f;
    for (int r = 0; r < 64; ++r) {
      sum += awL[r][h] * stg[r*33 + c];
      if (r == 63 || seL[r+1] != seL[r]) {
        atomicAdd(&acc_z[seL[r]*384 + h*32 + c], sum);
        sum = 0.f;
      }
    }
  }
  __syncthreads();

  for (int ch = 0; ch < 2; ++ch) {
    for (int i = tid; i < 64*144; i += 256) {
      int eloc = i / 144, jj = i - eloc*144;
      int j = ch*144 + jj;
      int h = j / 24;
      stg[eloc*145 + jj] = awL[eloc][h] * __bfloat162float(vph[deL[eloc]*288 + j]);
    }
    __syncthreads();
    for (int c = tid; c < 144; c += 256) {
      float sum = 0.f;
      for (int r = 0; r < 64; ++r) {
        sum += stg[r*145 + c];
        if (r == 63 || seL[r+1] != seL[r]) {
          atomicAdd(&acc_p[seL[r]*288 + ch*144 + c], sum);
          sum = 0.f;
        }
      }
    }
    __syncthreads();
  }
}

// -------- node output via MFMA: feats [32 x 960] @ Wo [960 x 384] --------
__global__ __launch_bounds__(256) void k_node_out_mfma(
    const float* __restrict__ rots, const float* __restrict__ trans,
    const ushort* __restrict__ wswz, const float* __restrict__ bo,
    const float* __restrict__ acc_o, const float* __restrict__ acc_p,
    const float* __restrict__ acc_z, float* __restrict__ out) {
  const int n0 = blockIdx.x * 32;
  const int tid = threadIdx.x;
  const int wave = tid >> 6, lane = tid & 63, quad = lane >> 4, l16 = lane & 15;
  __shared__ __align__(16) bf16 fbuf[32][968];
  __shared__ float RmL[32][9], tvL[32][3];
  for (int i = tid; i < 32*9; i += 256) {
    int nl = i/9, j = i - nl*9; int nd = n0 + nl;
    RmL[nl][j] = (nd < N_NODES) ? rots[nd*9 + j] : 0.f;
  }
  for (int i = tid; i < 32*3; i += 256) {
    int nl = i/3, j = i - nl*3; int nd = n0 + nl;
    tvL[nl][j] = (nd < N_NODES) ? 0.1f * trans[nd*3 + j] : 0.f;
  }
  __syncthreads();
  for (int i = tid; i < 32*192; i += 256) {
    int nl = i/192, c = i - nl*192; int nd = n0 + nl;
    fbuf[nl][c] = __float2bfloat16((nd < N_NODES) ? acc_o[nd*192 + c] : 0.f);
  }
  for (int i = tid; i < 32*96; i += 256) {
    int nl = i/96, pt = i - nl*96; int nd = n0 + nl;
    float r0 = 0.f, r1 = 0.f, r2 = 0.f, nm = 0.f;
    if (nd < N_NODES) {
      const float* Rm = RmL[nl];
      float v0 = acc_p[nd*288 + pt*3 + 0] - tvL[nl][0];
      float v1 = acc_p[nd*288 + pt*3 + 1] - tvL[nl][1];
      float v2 = acc_p[nd*288 + pt*3 + 2] - tvL[nl][2];
      r0 = Rm[0]*v0 + Rm[3]*v1 + Rm[6]*v2;
      r1 = Rm[1]*v0 + Rm[4]*v1 + Rm[7]*v2;
      r2 = Rm[2]*v0 + Rm[5]*v1 + Rm[8]*v2;
      nm = sqrtf(r0*r0 + r1*r1 + r2*r2 + 1e-8f);
    }
    fbuf[nl][192 + pt] = __float2bfloat16(r0);
    fbuf[nl][288 + pt] = __float2bfloat16(r1);
    fbuf[nl][384 + pt] = __float2bfloat16(r2);
    fbuf[nl][480 + pt] = __float2bfloat16(nm);
  }
  for (int i = tid; i < 32*384; i += 256) {
    int nl = i/384, c = i - nl*384; int nd = n0 + nl;
    fbuf[nl][576 + c] = __float2bfloat16((nd < N_NODES) ? acc_z[nd*384 + c] : 0.f);
  }
  __syncthreads();

  const int rowhalf = wave & 1, thalf = wave >> 1;
  f32x4 acc[12];
#pragma unroll
  for (int i = 0; i < 12; ++i) acc[i] = (f32x4){0.f, 0.f, 0.f, 0.f};
  const short8* bwo = (const short8*)(wswz + WOS);
#pragma unroll 2
  for (int kt = 0; kt < 30; ++kt) {
    short8 av = *(const short8*)&fbuf[rowhalf*16 + l16][kt*32 + quad*8];
#pragma unroll
    for (int nt = 0; nt < 12; ++nt) {
      short8 bv = bwo[(kt*24 + thalf*12 + nt)*64 + lane];
      acc[nt] = __builtin_amdgcn_mfma_f32_16x16x32_bf16(av, bv, acc[nt], 0, 0, 0);
    }
  }
#pragma unroll
  for (int nt = 0; nt < 12; ++nt) {
    int col = (thalf*12 + nt)*16 + l16;
    float bias = bo[col];
#pragma unroll
    for (int r = 0; r < 4; ++r) {
      int nd = n0 + rowhalf*16 + quad*4 + r;
      if (nd < N_NODES) out[nd*384 + col] = acc[nt][r] + bias;
    }
  }
}

extern "C" void kernel_launch(void* const* d_in, const int* in_sizes, int n_in,
                              void* d_out, int out_size, void* d_ws, size_t ws_size,
                              hipStream_t stream) {
  const float* s     = (const float*)d_in[0];
  const float* z     = (const float*)d_in[1];
  const int*   ei    = (const int*)d_in[2];
  const float* rots  = (const float*)d_in[3];
  const float* trans = (const float*)d_in[4];
  const float* mask  = (const float*)d_in[5];
  const float* Ww1 = (const float*)d_in[6];  const float* bw1 = (const float*)d_in[7];
  const float* Ww2 = (const float*)d_in[8];  const float* bw2 = (const float*)d_in[9];
  const float* Ww3 = (const float*)d_in[10]; const float* bw3 = (const float*)d_in[11];
  const float* Wv1 = (const float*)d_in[12]; const float* bv1 = (const float*)d_in[13];
  const float* Wv2 = (const float*)d_in[14]; const float* bv2 = (const float*)d_in[15];
  const float* Wv3 = (const float*)d_in[16]; const float* bv3 = (const float*)d_in[17];
  const float* Wq  = (const float*)d_in[18]; const float* bq  = (const float*)d_in[19];
  const float* Wkv = (const float*)d_in[20]; const float* bkv = (const float*)d_in[21];
  const float* Wb  = (const float*)d_in[22]; const float* bb  = (const float*)d_in[23];
  const float* Wdz = (const float*)d_in[24]; const float* bdz = (const float*)d_in[25];
  const float* Wo  = (const float*)d_in[26]; const float* bo  = (const float*)d_in[27];
  const float* hw  = (const float*)d_in[28];
  float* ws = (float*)d_ws;
  ushort* wswz = (ushort*)(ws + FP32_TOTAL);
  int* ib = (int*)(wswz + SWZ_TOTAL);
  float* out = (float*)d_out;
  ushort* sb = (ushort*)(ws + OFF_SB);
  ushort* sp = (ushort*)(ws + OFF_ACCZ);   // sp_src/sp_dst live here until k_zero_accz

  const int ntot = N_NODES * (192 + 288);
  k_init<<<(ntot + 255)/256, 256, 0, stream>>>(ws, ib);
  k_cast_s<<<(N_NODES*CS/4 + 255)/256, 256, 0, stream>>>(s, sb);

  SwzArgs A;
  const float* srcs[11] = {Ww1, Ww2, Ww3, Wb, Wv1, Wv2, Wv3, Wdz, Wq, Wkv, Wo};
  int offs[11]   = {WW1S, WW2S, WW3S, WBS, WV1S, WV2S, WV3S, WDZS, WQS, WKVS, WOS};
  int Ks[11]     = {896, 192, 192, 128, 512, 192, 192, 128, 384, 384, 960};
  int Nreals[11] = {192, 192, 12, 12, 192, 192, 192, 32, 144, 432, 384};
  int NTs[11]    = {12, 12, 1, 1, 12, 12, 12, 2, 9, 27, 24};
  int cum = 0;
  for (int m = 0; m < 11; ++m) {
    A.src[m] = srcs[m]; A.off[m] = offs[m]; A.start[m] = cum;
    A.Nreal[m] = Nreals[m]; A.NT[m] = NTs[m];
    cum += (Ks[m]/32) * NTs[m] * 512;
  }
  k_swz_all<<<(cum + 255)/256, 256, 0, stream>>>(A, wswz, cum);

  // sort first: logits are produced in sorted order
  k_hist<<<(N_EDGES + 255)/256, 256, 0, stream>>>(ei, ib);
  k_scan<<<1, 1024, 0, stream>>>(ib);
  k_scatter<<<(N_EDGES + 255)/256, 256, 0, stream>>>(ei, ib);

  k_node_proj_mfma<<<(N_NODES + 31)/32, 256, 0, stream>>>(
      sb, rots, trans, wswz, bq, bkv, ws);

  k_sp<<<(N_NODES + 31)/32, 256, 0, stream>>>(sb, wswz, sp);

  k_edge_logit_mfma<<<N_EDGES/64, 256, 0, stream>>>(
      sb, z, ei, mask, wswz,
      bw1, bw2, bw3, bb, hw,
      (const ushort*)(ws + OFF_QPTS), (const ushort*)(ws + OFF_KPTS),
      sp + SP_SRC_US, sp + SP_DST_US,
      ib, ws + OFF_LOGIT);

  // sp now dead; clear ACCZ for accum's atomics
  k_zero_accz<<<(N_NODES*384 + 255)/256, 256, 0, stream>>>(ws);

  k_softmax<<<(N_NODES*12 + 255)/256, 256, 0, stream>>>(ws + OFF_LOGIT, ib);

  k_edge_accum_mfma<<<N_EDGES/64, 256, 0, stream>>>(
      sb, z, ei, wswz,
      bv1, bv2, bv3, bdz,
      ws + OFF_LOGIT,
      (const bf16*)(ws + OFF_VPTSH), ib,
      ws + OFF_ACCO, ws + OFF_ACCP, ws + OFF_ACCZ);

  k_node_out_mfma<<<(N_NODES + 31)/32, 256, 0, stream>>>(
      rots, trans, wswz, bo,
      ws + OFF_ACCO, ws + OFF_ACCP, ws + OFF_ACCZ, out);
}

// Round 16
// 774.902 us; speedup vs baseline: 1.3691x; 1.0130x over previous
//
#include <hip/hip_runtime.h>
#include <hip/hip_bf16.h>
#include <math.h>

#define N_NODES 10000
#define N_EDGES 160000
#define CS 384
#define CZ 128
#define CH 192
#define NH 12
#define PQ 4
#define PV 8

typedef __hip_bfloat16 bf16;
typedef unsigned short ushort;
typedef __attribute__((ext_vector_type(8))) short short8;
typedef __attribute__((ext_vector_type(4))) short s16x4;
typedef __attribute__((ext_vector_type(4))) float f32x4;

__device__ __forceinline__ ushort cvt1(float f) {
  bf16 h = __float2bfloat16(f);
  return __builtin_bit_cast(unsigned short, h);
}
// fp32 -> bf16x8 fragment with guaranteed dwordx4 loads (idx 8-aligned)
__device__ __forceinline__ short8 lda8f(const float* p, int idx) {
  const f32x4* q = (const f32x4*)(p + idx);
  f32x4 a = q[0], b = q[1];
  short8 r;
  r[0] = (short)cvt1(a[0]); r[1] = (short)cvt1(a[1]);
  r[2] = (short)cvt1(a[2]); r[3] = (short)cvt1(a[3]);
  r[4] = (short)cvt1(b[0]); r[5] = (short)cvt1(b[1]);
  r[6] = (short)cvt1(b[2]); r[7] = (short)cvt1(b[3]);
  return r;
}
__device__ __forceinline__ float bf(ushort u) {
  return __bfloat162float(__builtin_bit_cast(bf16, u));
}

// ---- workspace layout (float offsets) ----
#define OFF_QPTS   0                              // N*144 bf16; after logit: sv (N*192 bf16)
#define OFF_KPTS   (OFF_QPTS + N_NODES*72)        // N*144 bf16 (part of sv region after logit)
#define OFF_VPTSH  (OFF_KPTS + N_NODES*72)        // N*288 bf16
#define OFF_SB     (OFF_VPTSH + N_NODES*144)      // N*384 bf16 (s pre-cast)
#define OFF_LOGIT  (OFF_SB + N_NODES*192)         // E*12 fp32 SORTED (becomes a after k_softmax)
#define OFF_AMAX   (OFF_LOGIT + N_EDGES*12)       // unused (kept for layout stability)
#define OFF_DENOM  (OFF_AMAX + N_NODES*12)        // unused
#define OFF_ACCO   (OFF_DENOM + N_NODES*12)       // N*192
#define OFF_ACCP   (OFF_ACCO + N_NODES*192)       // N*288
#define OFF_ACCZ   (OFF_ACCP + N_NODES*288)       // N*384 (holds sp_src/sp_dst bf16 until
                                                  //        k_zero_accz runs after logit)
#define FP32_TOTAL (OFF_ACCZ + N_NODES*384)

// sp (per-node W1 halves, bf16) live in the ACCZ region until accum needs it
#define SP_SRC_US  0                              // ushort offset within ACCZ region
#define SP_DST_US  (N_NODES*192)                  // 1.92M ushorts each; region holds 7.68M

// ---- swizzled weights (ushort offsets after FP32 region) ----
#define WW1S 0
#define WW2S 172032
#define WW3S 208896
#define WBS  211968
#define WV1S 214016
#define WV2S 312320
#define WV3S 349184
#define WDZS 386048
#define WQS  390144
#define WKVS 445440
#define WOS  611328
#define SWZ_TOTAL 979968

// ---- int region ----
#define IHIST   0
#define ICUR    10000
#define IROWPTR 20000
#define IPERM   30016

__global__ void k_init(float* __restrict__ ws, int* __restrict__ ib) {
  int idx = blockIdx.x * blockDim.x + threadIdx.x;
  const int ntot = N_NODES * (192 + 288);   // ACCO + ACCP only; ACCZ zeroed after logit
  if (idx < ntot) ws[OFF_ACCO + idx] = 0.0f;
  if (idx < N_NODES) ib[IHIST + idx] = 0;
}

__global__ void k_zero_accz(float* __restrict__ ws) {
  int idx = blockIdx.x * blockDim.x + threadIdx.x;
  if (idx < N_NODES*384) ws[OFF_ACCZ + idx] = 0.0f;
}

__global__ void k_cast_s(const float* __restrict__ s, ushort* __restrict__ sb) {
  int i = (blockIdx.x * 256 + threadIdx.x) * 4;
  if (i + 3 < N_NODES*CS) {
    f32x4 v = *(const f32x4*)(s + i);
    sb[i]   = cvt1(v[0]); sb[i+1] = cvt1(v[1]);
    sb[i+2] = cvt1(v[2]); sb[i+3] = cvt1(v[3]);
  }
}

// -------- merged weight swizzle (fp32 src -> bf16 B-fragment order), 11 matrices --------
struct SwzArgs {
  const float* src[11];
  int off[11], start[11], Nreal[11], NT[11];
};
__global__ void k_swz_all(SwzArgs A, ushort* __restrict__ dst, int grand) {
  int tid = blockIdx.x * blockDim.x + threadIdx.x;
  if (tid >= grand) return;
  int m = 0;
  while (m < 10 && tid >= A.start[m+1]) ++m;
  int t = tid - A.start[m];
  int j = t & 7, lane = (t >> 3) & 63, t2 = t >> 9;
  int nt = t2 % A.NT[m], kt = t2 / A.NT[m];
  int k = kt*32 + (lane >> 4)*8 + j;
  int n = nt*16 + (lane & 15);
  dst[A.off[m] + t] = (n < A.Nreal[m]) ? cvt1(A.src[m][k*A.Nreal[m] + n]) : (ushort)0;
}

// -------- counting sort by src --------
__global__ void k_hist(const int* __restrict__ ei, int* __restrict__ ib) {
  int e = blockIdx.x * 256 + threadIdx.x;
  if (e < N_EDGES) atomicAdd(&ib[IHIST + ei[N_EDGES + e]], 1);
}

__global__ __launch_bounds__(1024) void k_scan(int* __restrict__ ib) {
  __shared__ int csum[1024];
  int t = threadIdx.x;
  const int CHUNK = (N_NODES + 1023) / 1024;
  int beg = t * CHUNK;
  int end = beg + CHUNK; if (end > N_NODES) end = N_NODES;
  int s = 0;
  for (int i = beg; i < end && i < N_NODES; ++i) s += ib[IHIST + i];
  csum[t] = s;
  __syncthreads();
  for (int off = 1; off < 1024; off <<= 1) {
    int v = (t >= off) ? csum[t - off] : 0;
    __syncthreads();
    csum[t] += v;
    __syncthreads();
  }
  int run = (t == 0) ? 0 : csum[t - 1];
  for (int i = beg; i < end && i < N_NODES; ++i) {
    ib[IROWPTR + i] = run;
    ib[ICUR + i] = run;
    run += ib[IHIST + i];
  }
  if (t == 1023) ib[IROWPTR + N_NODES] = run;
}

__global__ void k_scatter(const int* __restrict__ ei, int* __restrict__ ib) {
  int e = blockIdx.x * 256 + threadIdx.x;
  if (e < N_EDGES) {
    int pos = atomicAdd(&ib[ICUR + ei[N_EDGES + e]], 1);
    ib[IPERM + pos] = e;
  }
}

// -------- per-node W1 halves: sp_src = s@W1[0:384], sp_dst = s@W1[384:768] (bf16, no bias) --------
// R14: validated (total 994.6 -> 785.0 us across R7+R8 changes; absmax unchanged).
__global__ __launch_bounds__(256) void k_sp(
    const ushort* __restrict__ sb, const ushort* __restrict__ wswz,
    ushort* __restrict__ sp) {
  const int n0 = blockIdx.x * 32;
  const int tid = threadIdx.x;
  const int wave = tid >> 6, lane = tid & 63, quad = lane >> 4, l16 = lane & 15;
  const int rowhalf = wave & 1, part = wave >> 1;   // part 0 = src half, 1 = dst half
  const int row = rowhalf*16 + l16;
  int nd = n0 + row;
  const int nclamp = (nd < N_NODES) ? nd : 0;
  f32x4 acc[12];
#pragma unroll
  for (int i = 0; i < 12; ++i) acc[i] = (f32x4){0.f, 0.f, 0.f, 0.f};
  const short8* bw = (const short8*)(wswz + WW1S);
#pragma unroll 2
  for (int kt = 0; kt < 12; ++kt) {
    short8 av = *(const short8*)(sb + nclamp*384 + kt*32 + quad*8);
    const short8* bk = bw + ((part*12 + kt)*12*64 + lane);
#pragma unroll
    for (int nt = 0; nt < 12; ++nt) {
      short8 bv = bk[nt*64];
      acc[nt] = __builtin_amdgcn_mfma_f32_16x16x32_bf16(av, bv, acc[nt], 0, 0, 0);
    }
  }
  ushort* dst = sp + (part ? SP_DST_US : SP_SRC_US);
#pragma unroll
  for (int nt = 0; nt < 12; ++nt) {
    int col = nt*16 + l16;
#pragma unroll
    for (int r = 0; r < 4; ++r) {
      int node = n0 + rowhalf*16 + quad*4 + r;
      if (node < N_NODES) dst[node*192 + col] = cvt1(acc[nt][r]);
    }
  }
}

// -------- per-node Wv1 dst half: sv = s@Wv1[0:384] (bf16, no bias) --------
// R14 new: same hoist pattern for the accum kernel. Output into the QPTS+KPTS region
// (q_pts/k_pts are dead after k_edge_logit; k_sv launches after it). 64 nodes/block.
__global__ __launch_bounds__(256) void k_sv(
    const ushort* __restrict__ sb, const ushort* __restrict__ wswz,
    ushort* __restrict__ sv) {
  const int n0 = blockIdx.x * 64;
  const int tid = threadIdx.x;
  const int wave = tid >> 6, lane = tid & 63, quad = lane >> 4, l16 = lane & 15;
  const int row = wave*16 + l16;
  int nd = n0 + row;
  const int nclamp = (nd < N_NODES) ? nd : 0;
  f32x4 acc[12];
#pragma unroll
  for (int i = 0; i < 12; ++i) acc[i] = (f32x4){0.f, 0.f, 0.f, 0.f};
  const short8* bw = (const short8*)(wswz + WV1S);
#pragma unroll 2
  for (int kt = 0; kt < 12; ++kt) {
    short8 av = *(const short8*)(sb + nclamp*384 + kt*32 + quad*8);
    const short8* bk = bw + (kt*12*64 + lane);
#pragma unroll
    for (int nt = 0; nt < 12; ++nt) {
      short8 bv = bk[nt*64];
      acc[nt] = __builtin_amdgcn_mfma_f32_16x16x32_bf16(av, bv, acc[nt], 0, 0, 0);
    }
  }
#pragma unroll
  for (int nt = 0; nt < 12; ++nt) {
    int col = nt*16 + l16;
#pragma unroll
    for (int r = 0; r < 4; ++r) {
      int node = n0 + wave*16 + quad*4 + r;
      if (node < N_NODES) sv[node*192 + col] = cvt1(acc[nt][r]);
    }
  }
}

// -------- node projection via MFMA: [32 x 384] @ [Wq|Wkv] (576 cols) --------
__global__ __launch_bounds__(256) void k_node_proj_mfma(
    const ushort* __restrict__ sb, const float* __restrict__ rots, const float* __restrict__ trans,
    const ushort* __restrict__ wswz,
    const float* __restrict__ bq, const float* __restrict__ bkv,
    float* __restrict__ ws) {
  const int n0 = blockIdx.x * 32;
  const int tid = threadIdx.x;
  const int wave = tid >> 6, lane = tid & 63, quad = lane >> 4, l16 = lane & 15;
  const int rowhalf = wave & 1, thalf = wave >> 1;
  __shared__ __align__(16) bf16 pbuf[32][584];
  __shared__ float RmL[32][9], tvL[32][3];
  for (int i = tid; i < 32*9; i += 256) {
    int nl = i/9, j = i - nl*9; int nd = n0 + nl;
    RmL[nl][j] = (nd < N_NODES) ? rots[nd*9 + j] : 0.f;
  }
  for (int i = tid; i < 32*3; i += 256) {
    int nl = i/3, j = i - nl*3; int nd = n0 + nl;
    tvL[nl][j] = (nd < N_NODES) ? 0.1f * trans[nd*3 + j] : 0.f;
  }

  const int row = rowhalf*16 + l16;
  int nd = n0 + row;
  const int nclamp = (nd < N_NODES) ? nd : 0;
  f32x4 acc[18];
#pragma unroll
  for (int i = 0; i < 18; ++i) acc[i] = (f32x4){0.f, 0.f, 0.f, 0.f};
  const short8* bq8 = (const short8*)(wswz + WQS);
  const short8* bkv8 = (const short8*)(wswz + WKVS);
#pragma unroll 2
  for (int kt = 0; kt < 12; ++kt) {
    short8 av = *(const short8*)(sb + nclamp*384 + kt*32 + quad*8);
#pragma unroll
    for (int nt = 0; nt < 18; ++nt) {
      int g = thalf*18 + nt;
      short8 bv = (g < 9) ? bq8[(kt*9 + g)*64 + lane]
                          : bkv8[(kt*27 + (g - 9))*64 + lane];
      acc[nt] = __builtin_amdgcn_mfma_f32_16x16x32_bf16(av, bv, acc[nt], 0, 0, 0);
    }
  }
#pragma unroll
  for (int nt = 0; nt < 18; ++nt) {
    int gcol = (thalf*18 + nt)*16 + l16;
    float bias = (gcol < 144) ? bq[gcol] : bkv[gcol - 144];
#pragma unroll
    for (int r = 0; r < 4; ++r)
      pbuf[rowhalf*16 + quad*4 + r][gcol] = __float2bfloat16(acc[nt][r] + bias);
  }
  __syncthreads();

  bf16* qpb = (bf16*)(ws + OFF_QPTS);
  bf16* kpb = (bf16*)(ws + OFF_KPTS);
  bf16* vph = (bf16*)(ws + OFF_VPTSH);
  for (int i = tid; i < 32*192; i += 256) {
    int nl = i / 192, p = i - nl*192;
    int node = n0 + nl;
    if (node >= N_NODES) continue;
    float c0, c1, c2;
    if (p < 48) {
      c0 = __bfloat162float(pbuf[nl][p]);
      c1 = __bfloat162float(pbuf[nl][48 + p]);
      c2 = __bfloat162float(pbuf[nl][96 + p]);
    } else {
      int q = p - 48;
      c0 = __bfloat162float(pbuf[nl][144 + q]);
      c1 = __bfloat162float(pbuf[nl][288 + q]);
      c2 = __bfloat162float(pbuf[nl][432 + q]);
    }
    const float* Rm = RmL[nl];
    const float* tv = tvL[nl];
    float r0 = Rm[0]*c0 + Rm[1]*c1 + Rm[2]*c2 + tv[0];
    float r1 = Rm[3]*c0 + Rm[4]*c1 + Rm[5]*c2 + tv[1];
    float r2 = Rm[6]*c0 + Rm[7]*c1 + Rm[8]*c2 + tv[2];
    if (p < 48) {
      int base = node*144 + p*3;
      qpb[base]   = __float2bfloat16(r0);
      qpb[base+1] = __float2bfloat16(r1);
      qpb[base+2] = __float2bfloat16(r2);
    } else {
      int q = p - 48; int h = q / 12, idx = q % 12;
      if (idx < PQ) {
        int base = node*144 + (h*PQ + idx)*3;
        kpb[base]   = __float2bfloat16(r0);
        kpb[base+1] = __float2bfloat16(r1);
        kpb[base+2] = __float2bfloat16(r2);
      } else {
        int base = node*288 + (h*PV + (idx - PQ))*3;
        vph[base]   = __float2bfloat16(r0);
        vph[base+1] = __float2bfloat16(r1);
        vph[base+2] = __float2bfloat16(r2);
      }
    }
  }
}

// ---------------- fused edge logit via MFMA, M=64 tile, SORTED edges ----------------
// R8/R14: W1 src/dst halves hoisted to per-node sp (k_sp) — K-loop 28 kt -> 4 kt (z only),
// node contributions added in the epilogue as gathered bf16. Measured: total -> 785us.
__global__ __launch_bounds__(256) void k_edge_logit_mfma(
    const ushort* __restrict__ sb, const float* __restrict__ zp, const int* __restrict__ ei,
    const float* __restrict__ mask,
    const ushort* __restrict__ wswz,
    const float* __restrict__ bw1, const float* __restrict__ bw2, const float* __restrict__ bw3,
    const float* __restrict__ bb, const float* __restrict__ hw,
    const ushort* __restrict__ qpb, const ushort* __restrict__ kpb,
    const ushort* __restrict__ sps, const ushort* __restrict__ spd,
    const int* __restrict__ ib,
    float* __restrict__ logit) {
  const int e0 = blockIdx.x * 64;
  const int tid = threadIdx.x;
  const int wave = tid >> 6, lane = tid & 63, quad = lane >> 4, l16 = lane & 15;
  __shared__ __align__(16) bf16 hbuf[64][200];   // 25.6 KB, rows strictly wave-owned
  __shared__ int seL[64], deL[64], eIdL[64];
  if (tid < 64) {
    int e = ib[IPERM + e0 + tid];
    eIdL[tid] = e; deL[tid] = ei[e]; seL[tid] = ei[N_EDGES + e];
  }
  __syncthreads();

  const int r0 = wave*16 + l16;
  const int ez0 = eIdL[r0];

  f32x4 acc0[12];
#pragma unroll
  for (int i = 0; i < 12; ++i) acc0[i] = (f32x4){0.f, 0.f, 0.f, 0.f};
  f32x4 accB0 = (f32x4){0.f, 0.f, 0.f, 0.f};
  const short8* bw = (const short8*)(wswz + WW1S);
  const short8* bB8 = (const short8*)(wswz + WBS);
  // W1, z-part only (global K 768..896 = swizzled kt 24..27) — fuse Wb (identical A)
#pragma unroll 2
  for (int kt = 0; kt < 4; ++kt) {
    int k0 = kt*32 + quad*8;
    short8 a0 = lda8f(zp, ez0*128 + k0);
    const short8* bk = bw + ((24 + kt)*12*64 + lane);
#pragma unroll
    for (int nt = 0; nt < 12; ++nt) {
      short8 bv = bk[nt*64];
      acc0[nt] = __builtin_amdgcn_mfma_f32_16x16x32_bf16(a0, bv, acc0[nt], 0, 0, 0);
    }
    short8 bvB = bB8[kt*64 + lane];
    accB0 = __builtin_amdgcn_mfma_f32_16x16x32_bf16(a0, bvB, accB0, 0, 0, 0);
  }
  // W1 epilogue: add per-node sp halves (gathered bf16) + bias, relu, store
#pragma unroll
  for (int nt = 0; nt < 12; ++nt) {
    int col = nt*16 + l16;
    float bcol = bw1[col];
#pragma unroll
    for (int r = 0; r < 4; ++r) {
      int row = wave*16 + quad*4 + r;
      float v = acc0[nt][r] + bcol
              + bf(sps[seL[row]*192 + col])
              + bf(spd[deL[row]*192 + col]);
      hbuf[row][col] = __float2bfloat16(fmaxf(v, 0.f));
    }
  }

  // W2
#pragma unroll
  for (int i = 0; i < 12; ++i) acc0[i] = (f32x4){0.f, 0.f, 0.f, 0.f};
  bw = (const short8*)(wswz + WW2S);
#pragma unroll
  for (int kt = 0; kt < 6; ++kt) {
    short8 a0 = *(const short8*)&hbuf[r0][kt*32 + quad*8];
    const short8* bk = bw + (kt*12*64 + lane);
#pragma unroll
    for (int nt = 0; nt < 12; ++nt) {
      short8 bv = bk[nt*64];
      acc0[nt] = __builtin_amdgcn_mfma_f32_16x16x32_bf16(a0, bv, acc0[nt], 0, 0, 0);
    }
  }
#pragma unroll
  for (int nt = 0; nt < 12; ++nt) {
    float bcol = bw2[nt*16 + l16];
#pragma unroll
    for (int r = 0; r < 4; ++r)
      hbuf[wave*16 + quad*4 + r][nt*16 + l16] =
          __float2bfloat16(fmaxf(acc0[nt][r] + bcol, 0.f));
  }

  // W3
  f32x4 accW0 = (f32x4){0.f, 0.f, 0.f, 0.f};
  const short8* b3 = (const short8*)(wswz + WW3S);
#pragma unroll
  for (int kt = 0; kt < 6; ++kt) {
    short8 a0 = *(const short8*)&hbuf[r0][kt*32 + quad*8];
    short8 bv = b3[kt*64 + lane];
    accW0 = __builtin_amdgcn_mfma_f32_16x16x32_bf16(a0, bv, accW0, 0, 0, 0);
  }

  if (l16 < 12) {
    const int h = l16;
    float hv = hw[h];
    float hws = logf(1.0f + expf(hv)) * 0.1360827634879543f;
    float b3c = bw3[h], bbc = bb[h];
#pragma unroll
    for (int r = 0; r < 4; ++r) {
      int eloc = wave*16 + quad*4 + r;
      int se = seL[eloc], de = deL[eloc];
      float v = (accW0[r] + b3c) * 0.041666666666666664f + 0.5773502691896258f * (accB0[r] + bbc);
      int qb = se*144 + h*12;
      int kb = de*144 + h*12;
      float pa = 0.f;
#pragma unroll
      for (int t3 = 0; t3 < 3; ++t3) {
        s16x4 qv = *(const s16x4*)(qpb + qb + t3*4);
        s16x4 kv = *(const s16x4*)(kpb + kb + t3*4);
#pragma unroll
        for (int u = 0; u < 4; ++u) {
          float d = bf((ushort)qv[u]) - bf((ushort)kv[u]);
          pa += d*d;
        }
      }
      v -= 0.5f * hws * pa;
      v += 100000.0f * (mask[de] * mask[se] - 1.0f);
      logit[(e0 + eloc)*12 + h] = v;   // sorted position
    }
  }
}

// ------- per-(node,head) softmax over contiguous sorted segments; no atomics -------
__global__ void k_softmax(float* __restrict__ a, const int* __restrict__ ib) {
  int t = blockIdx.x * 256 + threadIdx.x;
  if (t >= N_NODES * 12) return;
  int n = t / 12, h = t - n*12;
  int b = ib[IROWPTR + n], e = ib[IROWPTR + n + 1];
  if (b == e) return;
  float m = -3.4e38f;
  for (int j = b; j < e; ++j) m = fmaxf(m, a[j*12 + h]);
  float s = 0.f;
  for (int j = b; j < e; ++j) {
    float ex = expf(a[j*12 + h] - m);
    s += ex;
    a[j*12 + h] = ex;
  }
  float inv = 1.f / (s + 1e-16f);
  for (int j = b; j < e; ++j) a[j*12 + h] *= inv;
}

// ------- fused edge accum via MFMA over SORTED edges + segmented scatter -------
// R14: Wv1 dst half hoisted to per-node sv (k_sv) — V1 K-loop 16 kt -> 4 kt (z only,
// Wdz fused); sv added in the V1 epilogue as gathered bf16. Scatter phases = the
// R7-measured block-cooperative version (294.6us; wave-private variant refuted in R8).
__global__ __launch_bounds__(256) void k_edge_accum_mfma(
    const float* __restrict__ zp, const int* __restrict__ ei,
    const ushort* __restrict__ wswz,
    const float* __restrict__ bv1, const float* __restrict__ bv2, const float* __restrict__ bv3,
    const float* __restrict__ bdz,
    const float* __restrict__ aS,
    const ushort* __restrict__ sv,
    const bf16* __restrict__ vph, const int* __restrict__ ib,
    float* __restrict__ acc_o, float* __restrict__ acc_p, float* __restrict__ acc_z) {
  const int p0 = blockIdx.x * 64;
  const int tid = threadIdx.x;
  const int wave = tid >> 6, lane = tid & 63, quad = lane >> 4, l16 = lane & 15;
  __shared__ __align__(16) unsigned char smem[64*193*4];
  __shared__ float awL[64][12];
  __shared__ int seL[64], deL[64], eIdL[64];
  bf16* hb = (bf16*)smem;
  float* stg = (float*)smem;
  if (tid < 64) {
    int e = ib[IPERM + p0 + tid];
    eIdL[tid] = e;
    deL[tid] = ei[e];
    seL[tid] = ei[N_EDGES + e];
  }
  __syncthreads();
  for (int i = tid; i < 64*12; i += 256)
    (&awL[0][0])[i] = aS[p0*12 + i];   // contiguous, already normalized

  const int arow = wave*16 + l16;
  const int eid  = eIdL[arow];

  f32x4 acc[12];
#pragma unroll
  for (int i = 0; i < 12; ++i) acc[i] = (f32x4){0.f, 0.f, 0.f, 0.f};
  f32x4 apz[2];
  apz[0] = (f32x4){0.f, 0.f, 0.f, 0.f};
  apz[1] = (f32x4){0.f, 0.f, 0.f, 0.f};
  const short8* bw = (const short8*)(wswz + WV1S);
  const short8* bz = (const short8*)(wswz + WDZS);
  // V1, z-part only (global K 384..512 = swizzled kt 12..15) — fuse Wdz (identical A)
#pragma unroll 2
  for (int kt = 12; kt < 16; ++kt) {
    int kz = (kt - 12)*32 + quad*8;
    short8 av = lda8f(zp, eid*128 + kz);
    const short8* bk = bw + (kt*12*64 + lane);
#pragma unroll
    for (int nt = 0; nt < 12; ++nt) {
      short8 bv = bk[nt*64];
      acc[nt] = __builtin_amdgcn_mfma_f32_16x16x32_bf16(av, bv, acc[nt], 0, 0, 0);
    }
#pragma unroll
    for (int nt = 0; nt < 2; ++nt) {
      short8 bvz = bz[((kt - 12)*2 + nt)*64 + lane];
      apz[nt] = __builtin_amdgcn_mfma_f32_16x16x32_bf16(av, bvz, apz[nt], 0, 0, 0);
    }
  }
  // V1 epilogue: add per-node sv (gathered bf16) + bias, relu (hb rows wave-owned)
#pragma unroll
  for (int nt = 0; nt < 12; ++nt) {
    int col = nt*16 + l16;
    float bcol = bv1[col];
#pragma unroll
    for (int r = 0; r < 4; ++r) {
      int eloc = wave*16 + quad*4 + r;
      float v = acc[nt][r] + bcol + bf(sv[deL[eloc]*192 + col]);
      hb[eloc*200 + col] = __float2bfloat16(fmaxf(v, 0.f));
    }
  }

  // V2
#pragma unroll
  for (int i = 0; i < 12; ++i) acc[i] = (f32x4){0.f, 0.f, 0.f, 0.f};
  bw = (const short8*)(wswz + WV2S);
#pragma unroll
  for (int kt = 0; kt < 6; ++kt) {
    short8 av = *(const short8*)&hb[(wave*16 + l16)*200 + kt*32 + quad*8];
    const short8* bk = bw + (kt*12*64 + lane);
#pragma unroll
    for (int nt = 0; nt < 12; ++nt) {
      short8 bv = bk[nt*64];
      acc[nt] = __builtin_amdgcn_mfma_f32_16x16x32_bf16(av, bv, acc[nt], 0, 0, 0);
    }
  }
#pragma unroll
  for (int nt = 0; nt < 12; ++nt) {
    float bcol = bv2[nt*16 + l16];
#pragma unroll
    for (int r = 0; r < 4; ++r)
      hb[(wave*16 + quad*4 + r)*200 + nt*16 + l16] =
          __float2bfloat16(fmaxf(acc[nt][r] + bcol, 0.f));
  }

  // V3
#pragma unroll
  for (int i = 0; i < 12; ++i) acc[i] = (f32x4){0.f, 0.f, 0.f, 0.f};
  bw = (const short8*)(wswz + WV3S);
#pragma unroll
  for (int kt = 0; kt < 6; ++kt) {
    short8 av = *(const short8*)&hb[(wave*16 + l16)*200 + kt*32 + quad*8];
    const short8* bk = bw + (kt*12*64 + lane);
#pragma unroll
    for (int nt = 0; nt < 12; ++nt) {
      short8 bv = bk[nt*64];
      acc[nt] = __builtin_amdgcn_mfma_f32_16x16x32_bf16(av, bv, acc[nt], 0, 0, 0);
    }
  }
  __syncthreads();   // hb (all waves) dead; stg aliasing + awL cross-wave reads begin

#pragma unroll
  for (int nt = 0; nt < 12; ++nt) {
    int col = nt*16 + l16;
    float bcol = bv3[col];
#pragma unroll
    for (int r = 0; r < 4; ++r) {
      int eloc = wave*16 + quad*4 + r;
      stg[eloc*193 + col] = awL[eloc][nt] * (acc[nt][r] + bcol);
    }
  }
  __syncthreads();
  for (int c = tid; c < 192; c += 256) {
    float sum = 0.f;
    for (int r = 0; r < 64; ++r) {
      sum += stg[r*193 + c];
      if (r == 63 || seL[r+1] != seL[r]) {
        atomicAdd(&acc_o[seL[r]*192 + c], sum);
        sum = 0.f;
      }
    }
  }
  __syncthreads();

#pragma unroll
  for (int nt = 0; nt < 2; ++nt) {
    int c = nt*16 + l16;
    float bcol = bdz[c];
#pragma unroll
    for (int r = 0; r < 4; ++r) {
      int eloc = wave*16 + quad*4 + r;
      stg[eloc*33 + c] = apz[nt][r] + bcol;
    }
  }
  __syncthreads();
  for (int p = tid; p < 384; p += 256) {
    int h = p >> 5, c = p & 31;
    float sum = 0.f;
    for (int r = 0; r < 64; ++r) {
      sum += awL[r][h] * stg[r*33 + c];
      if (r == 63 || seL[r+1] != seL[r]) {
        atomicAdd(&acc_z[seL[r]*384 + h*32 + c], sum);
        sum = 0.f;
      }
    }
  }
  __syncthreads();

  for (int ch = 0; ch < 2; ++ch) {
    for (int i = tid; i < 64*144; i += 256) {
      int eloc = i / 144, jj = i - eloc*144;
      int j = ch*144 + jj;
      int h = j / 24;
      stg[eloc*145 + jj] = awL[eloc][h] * __bfloat162float(vph[deL[eloc]*288 + j]);
    }
    __syncthreads();
    for (int c = tid; c < 144; c += 256) {
      float sum = 0.f;
      for (int r = 0; r < 64; ++r) {
        sum += stg[r*145 + c];
        if (r == 63 || seL[r+1] != seL[r]) {
          atomicAdd(&acc_p[seL[r]*288 + ch*144 + c], sum);
          sum = 0.f;
        }
      }
    }
    __syncthreads();
  }
}

// -------- node output via MFMA: feats [32 x 960] @ Wo [960 x 384] --------
__global__ __launch_bounds__(256) void k_node_out_mfma(
    const float* __restrict__ rots, const float* __restrict__ trans,
    const ushort* __restrict__ wswz, const float* __restrict__ bo,
    const float* __restrict__ acc_o, const float* __restrict__ acc_p,
    const float* __restrict__ acc_z, float* __restrict__ out) {
  const int n0 = blockIdx.x * 32;
  const int tid = threadIdx.x;
  const int wave = tid >> 6, lane = tid & 63, quad = lane >> 4, l16 = lane & 15;
  __shared__ __align__(16) bf16 fbuf[32][968];
  __shared__ float RmL[32][9], tvL[32][3];
  for (int i = tid; i < 32*9; i += 256) {
    int nl = i/9, j = i - nl*9; int nd = n0 + nl;
    RmL[nl][j] = (nd < N_NODES) ? rots[nd*9 + j] : 0.f;
  }
  for (int i = tid; i < 32*3; i += 256) {
    int nl = i/3, j = i - nl*3; int nd = n0 + nl;
    tvL[nl][j] = (nd < N_NODES) ? 0.1f * trans[nd*3 + j] : 0.f;
  }
  __syncthreads();
  for (int i = tid; i < 32*192; i += 256) {
    int nl = i/192, c = i - nl*192; int nd = n0 + nl;
    fbuf[nl][c] = __float2bfloat16((nd < N_NODES) ? acc_o[nd*192 + c] : 0.f);
  }
  for (int i = tid; i < 32*96; i += 256) {
    int nl = i/96, pt = i - nl*96; int nd = n0 + nl;
    float r0 = 0.f, r1 = 0.f, r2 = 0.f, nm = 0.f;
    if (nd < N_NODES) {
      const float* Rm = RmL[nl];
      float v0 = acc_p[nd*288 + pt*3 + 0] - tvL[nl][0];
      float v1 = acc_p[nd*288 + pt*3 + 1] - tvL[nl][1];
      float v2 = acc_p[nd*288 + pt*3 + 2] - tvL[nl][2];
      r0 = Rm[0]*v0 + Rm[3]*v1 + Rm[6]*v2;
      r1 = Rm[1]*v0 + Rm[4]*v1 + Rm[7]*v2;
      r2 = Rm[2]*v0 + Rm[5]*v1 + Rm[8]*v2;
      nm = sqrtf(r0*r0 + r1*r1 + r2*r2 + 1e-8f);
    }
    fbuf[nl][192 + pt] = __float2bfloat16(r0);
    fbuf[nl][288 + pt] = __float2bfloat16(r1);
    fbuf[nl][384 + pt] = __float2bfloat16(r2);
    fbuf[nl][480 + pt] = __float2bfloat16(nm);
  }
  for (int i = tid; i < 32*384; i += 256) {
    int nl = i/384, c = i - nl*384; int nd = n0 + nl;
    fbuf[nl][576 + c] = __float2bfloat16((nd < N_NODES) ? acc_z[nd*384 + c] : 0.f);
  }
  __syncthreads();

  const int rowhalf = wave & 1, thalf = wave >> 1;
  f32x4 acc[12];
#pragma unroll
  for (int i = 0; i < 12; ++i) acc[i] = (f32x4){0.f, 0.f, 0.f, 0.f};
  const short8* bwo = (const short8*)(wswz + WOS);
#pragma unroll 2
  for (int kt = 0; kt < 30; ++kt) {
    short8 av = *(const short8*)&fbuf[rowhalf*16 + l16][kt*32 + quad*8];
#pragma unroll
    for (int nt = 0; nt < 12; ++nt) {
      short8 bv = bwo[(kt*24 + thalf*12 + nt)*64 + lane];
      acc[nt] = __builtin_amdgcn_mfma_f32_16x16x32_bf16(av, bv, acc[nt], 0, 0, 0);
    }
  }
#pragma unroll
  for (int nt = 0; nt < 12; ++nt) {
    int col = (thalf*12 + nt)*16 + l16;
    float bias = bo[col];
#pragma unroll
    for (int r = 0; r < 4; ++r) {
      int nd = n0 + rowhalf*16 + quad*4 + r;
      if (nd < N_NODES) out[nd*384 + col] = acc[nt][r] + bias;
    }
  }
}

extern "C" void kernel_launch(void* const* d_in, const int* in_sizes, int n_in,
                              void* d_out, int out_size, void* d_ws, size_t ws_size,
                              hipStream_t stream) {
  const float* s     = (const float*)d_in[0];
  const float* z     = (const float*)d_in[1];
  const int*   ei    = (const int*)d_in[2];
  const float* rots  = (const float*)d_in[3];
  const float* trans = (const float*)d_in[4];
  const float* mask  = (const float*)d_in[5];
  const float* Ww1 = (const float*)d_in[6];  const float* bw1 = (const float*)d_in[7];
  const float* Ww2 = (const float*)d_in[8];  const float* bw2 = (const float*)d_in[9];
  const float* Ww3 = (const float*)d_in[10]; const float* bw3 = (const float*)d_in[11];
  const float* Wv1 = (const float*)d_in[12]; const float* bv1 = (const float*)d_in[13];
  const float* Wv2 = (const float*)d_in[14]; const float* bv2 = (const float*)d_in[15];
  const float* Wv3 = (const float*)d_in[16]; const float* bv3 = (const float*)d_in[17];
  const float* Wq  = (const float*)d_in[18]; const float* bq  = (const float*)d_in[19];
  const float* Wkv = (const float*)d_in[20]; const float* bkv = (const float*)d_in[21];
  const float* Wb  = (const float*)d_in[22]; const float* bb  = (const float*)d_in[23];
  const float* Wdz = (const float*)d_in[24]; const float* bdz = (const float*)d_in[25];
  const float* Wo  = (const float*)d_in[26]; const float* bo  = (const float*)d_in[27];
  const float* hw  = (const float*)d_in[28];
  float* ws = (float*)d_ws;
  ushort* wswz = (ushort*)(ws + FP32_TOTAL);
  int* ib = (int*)(wswz + SWZ_TOTAL);
  float* out = (float*)d_out;
  ushort* sb = (ushort*)(ws + OFF_SB);
  ushort* sp = (ushort*)(ws + OFF_ACCZ);   // sp_src/sp_dst live here until k_zero_accz
  ushort* sv = (ushort*)(ws + OFF_QPTS);   // sv lives here after logit (qpts/kpts dead)

  const int ntot = N_NODES * (192 + 288);
  k_init<<<(ntot + 255)/256, 256, 0, stream>>>(ws, ib);
  k_cast_s<<<(N_NODES*CS/4 + 255)/256, 256, 0, stream>>>(s, sb);

  SwzArgs A;
  const float* srcs[11] = {Ww1, Ww2, Ww3, Wb, Wv1, Wv2, Wv3, Wdz, Wq, Wkv, Wo};
  int offs[11]   = {WW1S, WW2S, WW3S, WBS, WV1S, WV2S, WV3S, WDZS, WQS, WKVS, WOS};
  int Ks[11]     = {896, 192, 192, 128, 512, 192, 192, 128, 384, 384, 960};
  int Nreals[11] = {192, 192, 12, 12, 192, 192, 192, 32, 144, 432, 384};
  int NTs[11]    = {12, 12, 1, 1, 12, 12, 12, 2, 9, 27, 24};
  int cum = 0;
  for (int m = 0; m < 11; ++m) {
    A.src[m] = srcs[m]; A.off[m] = offs[m]; A.start[m] = cum;
    A.Nreal[m] = Nreals[m]; A.NT[m] = NTs[m];
    cum += (Ks[m]/32) * NTs[m] * 512;
  }
  k_swz_all<<<(cum + 255)/256, 256, 0, stream>>>(A, wswz, cum);

  // sort first: logits are produced in sorted order
  k_hist<<<(N_EDGES + 255)/256, 256, 0, stream>>>(ei, ib);
  k_scan<<<1, 1024, 0, stream>>>(ib);
  k_scatter<<<(N_EDGES + 255)/256, 256, 0, stream>>>(ei, ib);

  k_node_proj_mfma<<<(N_NODES + 31)/32, 256, 0, stream>>>(
      sb, rots, trans, wswz, bq, bkv, ws);

  k_sp<<<(N_NODES + 31)/32, 256, 0, stream>>>(sb, wswz, sp);

  k_edge_logit_mfma<<<N_EDGES/64, 256, 0, stream>>>(
      sb, z, ei, mask, wswz,
      bw1, bw2, bw3, bb, hw,
      (const ushort*)(ws + OFF_QPTS), (const ushort*)(ws + OFF_KPTS),
      sp + SP_SRC_US, sp + SP_DST_US,
      ib, ws + OFF_LOGIT);

  // qpts/kpts now dead -> compute sv there; sp dead -> clear ACCZ for accum's atomics
  k_sv<<<(N_NODES + 63)/64, 256, 0, stream>>>(sb, wswz, sv);
  k_zero_accz<<<(N_NODES*384 + 255)/256, 256, 0, stream>>>(ws);

  k_softmax<<<(N_NODES*12 + 255)/256, 256, 0, stream>>>(ws + OFF_LOGIT, ib);

  k_edge_accum_mfma<<<N_EDGES/64, 256, 0, stream>>>(
      z, ei, wswz,
      bv1, bv2, bv3, bdz,
      ws + OFF_LOGIT,
      sv,
      (const bf16*)(ws + OFF_VPTSH), ib,
      ws + OFF_ACCO, ws + OFF_ACCP, ws + OFF_ACCZ);

  k_node_out_mfma<<<(N_NODES + 31)/32, 256, 0, stream>>>(
      rots, trans, wswz, bo,
      ws + OFF_ACCO, ws + OFF_ACCP, ws + OFF_ACCZ, out);
}